// Round 8
// baseline (193.971 us; speedup 1.0000x reference)
//
#include <hip/hip_runtime.h>
#include <stdint.h>

typedef unsigned short u16;
typedef __attribute__((ext_vector_type(8))) short s16x8;   // bf16x8 MFMA frag (4 VGPRs)
typedef __attribute__((ext_vector_type(4))) float f32x4;   // MFMA C/D frag
typedef __attribute__((ext_vector_type(4))) unsigned short u16x4;
typedef __attribute__((ext_vector_type(2))) unsigned int u32x2;

// ---------------- helpers ----------------

__device__ __forceinline__ u16 f2bf(float f) {
  unsigned u = __float_as_uint(f);
  unsigned r = (u + 0x7fffu + ((u >> 16) & 1u)) >> 16;   // RNE
  return (u16)r;
}
__device__ __forceinline__ unsigned cvt_pk(float lo, float hi) {
  unsigned r;
  asm("v_cvt_pk_bf16_f32 %0, %1, %2" : "=v"(r) : "v"(lo), "v"(hi));
  return r;
}
__device__ __forceinline__ float exp2fast(float x) {
  return __builtin_amdgcn_exp2f(x);   // v_exp_f32: D = 2^S0
}

typedef const __attribute__((address_space(1))) unsigned int* gas_ptr;
typedef __attribute__((address_space(3))) unsigned int* las_ptr;

__device__ __forceinline__ void g2l16(const void* g, void* l) {
  __builtin_amdgcn_global_load_lds((gas_ptr)g, (las_ptr)l, 16, 0, 0);
}

__device__ __forceinline__ void cvt4(const float* __restrict__ in, u16* __restrict__ out) {
  const f32x4 v = *(const f32x4*)in;
  u16x4 o;
  o[0] = f2bf(v[0]); o[1] = f2bf(v[1]); o[2] = f2bf(v[2]); o[3] = f2bf(v[3]);
  *(u16x4*)out = o;
}

// ---------------- fused prep: all bf16 conversions + trig tables ----------------

__global__ void prep_kernel(const float* __restrict__ x,  const float* __restrict__ wq,
                            const float* __restrict__ wk, const float* __restrict__ wv,
                            const float* __restrict__ wo,
                            u16* __restrict__ xb, u16* __restrict__ wcat, u16* __restrict__ wob,
                            float* __restrict__ cosT, float* __restrict__ sinT) {
  const long id = (long)blockIdx.x * 256 + threadIdx.x;
  if (id < 262144) {                       // wq -> wcat rows 0..1023
    cvt4(wq + id * 4, wcat + id * 4);
  } else if (id < 327680) {                // wk -> wcat rows 1024..1279
    const long i = id - 262144;
    cvt4(wk + i * 4, wcat + 1048576 + i * 4);
  } else if (id < 393216) {                // wv -> wcat rows 1280..1535
    const long i = id - 327680;
    cvt4(wv + i * 4, wcat + 1310720 + i * 4);
  } else if (id < 655360) {                // wo
    const long i = id - 393216;
    cvt4(wo + i * 4, wob + i * 4);
  } else if (id < 671744) {                // trig tables, 4 entries per id
    const long t = id - 655360;
#pragma unroll
    for (int u = 0; u < 4; ++u) {
      const long idx = t * 4 + u;
      const int s = (int)(idx >> 5), j = (int)(idx & 31);
      const double invd = exp(-(double)j * 0.2878231366242558);  // ln(10000)/32
      const float a = (float)s * (float)invd;
      cosT[idx] = cosf(a);
      sinT[idx] = sinf(a);
    }
  } else {                                 // x
    const long i = id - 671744;
    cvt4(x + i * 4, xb + i * 4);
  }
}

// ---------------- fused QKV projection GEMM (BK=64, dbuf, swizzled, XCD-chunked) ----------------
// flat grid 384: xcd = bid&7 owns A-rows [4*xcd, 4*xcd+4) x all 12 W-cols ->
// per-XCD L2 working set = A 1MB + W 3MB. arowBlk=(bid&7)*4+((bid>>3)&3), wcolBlk=bid>>5.
// V blocks (wcolBlk >= 10) use swapped MFMA operands -> transposed acc -> coalesced V^T store.

__global__ __launch_bounds__(256, 2) void gemm_qkv_kernel(
    const u16* __restrict__ A, const u16* __restrict__ W,
    u16* __restrict__ qo, u16* __restrict__ ko, u16* __restrict__ vto,
    const float* __restrict__ cosT, const float* __restrict__ sinT) {
  const int K = 1024;
  __shared__ __align__(16) u16 As[2][128 * 64];
  __shared__ __align__(16) u16 Bs[2][128 * 64];
  const int tid = threadIdx.x;
  const int lane = tid & 63;
  const int wave = tid >> 6;
  const int g = lane >> 4, l15 = lane & 15;
  const int wr = wave >> 1, wc = wave & 1;
  const int bid = blockIdx.x;
  const int arowBlk = (bid & 7) * 4 + ((bid >> 3) & 3);
  const int wcolBlk = bid >> 5;
  const long arow0 = (long)arowBlk * 128;
  const long wrow0 = (long)wcolBlk * 128;
  const u16* Ab = A + arow0 * K;
  const u16* Wb = W + wrow0 * K;
  const bool isV = (wcolBlk >= 10);

  auto STAGE = [&](int buf, int k0) {
#pragma unroll
    for (int i = 0; i < 4; ++i) {
      const int lbase = i * 256 + wave * 64;
      const int c = lbase + lane;
      const int r = c >> 3, c8 = c & 7;
      const int cs = (c8 ^ (r & 7)) * 8;       // inverse-swizzled source (rule #21)
      g2l16(Ab + (long)r * K + k0 + cs, (char*)As[buf] + lbase * 16);
      g2l16(Wb + (long)r * K + k0 + cs, (char*)Bs[buf] + lbase * 16);
    }
  };

  f32x4 acc[4][4] = {};
  int cur = 0;
  STAGE(0, 0);

  for (int k0 = 0; k0 < K; k0 += 64) {
    if (k0 + 64 < K) {
      STAGE(cur ^ 1, k0 + 64);
      asm volatile("s_waitcnt vmcnt(8)" ::: "memory");   // cur's 8 loads done; next 8 in flight
    } else {
      asm volatile("s_waitcnt vmcnt(0)" ::: "memory");
    }
    __builtin_amdgcn_s_barrier();
#pragma unroll
    for (int ks = 0; ks < 2; ++ks) {
      s16x8 af[4], bfr[4];
#pragma unroll
      for (int m = 0; m < 4; ++m) {
        const int row = wr * 64 + m * 16 + l15;
        af[m] = *(const s16x8*)((const char*)As[cur] + row * 128 + (((ks * 4 + g) ^ (row & 7)) << 4));
      }
#pragma unroll
      for (int n = 0; n < 4; ++n) {
        const int row = wc * 64 + n * 16 + l15;
        bfr[n] = *(const s16x8*)((const char*)Bs[cur] + row * 128 + (((ks * 4 + g) ^ (row & 7)) << 4));
      }
      __builtin_amdgcn_s_setprio(1);
      if (!isV) {
#pragma unroll
        for (int m = 0; m < 4; ++m)
#pragma unroll
          for (int n = 0; n < 4; ++n)
            acc[m][n] = __builtin_amdgcn_mfma_f32_16x16x32_bf16(af[m], bfr[n], acc[m][n], 0, 0, 0);
      } else {
        // swapped: acc[mw][nx], rows = W-dim (d), cols = X-dim (s)
#pragma unroll
        for (int m = 0; m < 4; ++m)
#pragma unroll
          for (int n = 0; n < 4; ++n)
            acc[m][n] = __builtin_amdgcn_mfma_f32_16x16x32_bf16(bfr[m], af[n], acc[m][n], 0, 0, 0);
      }
      __builtin_amdgcn_s_setprio(0);
    }
    __builtin_amdgcn_s_barrier();
    cur ^= 1;
  }

  const int colBase = (int)wrow0 + wc * 64;
  const int j0 = l15;
  const float QSCALE = 0.18033688011112042f;   // 0.125 * log2(e): softmax done in base 2

  if (colBase < 1024) {                       // ---- Q: rope + scale ----
    const int h2 = colBase >> 6;
#pragma unroll
    for (int m = 0; m < 4; ++m) {
      const int grow = (int)arow0 + wr * 64 + m * 16 + g * 4;
#pragma unroll
      for (int r = 0; r < 4; ++r) {
        const int row = grow + r;
        const int s = row & 2047, bb = row >> 11;
        const long ob = (((long)(bb * 16 + h2)) * 2048 + s) * 64;
        const float c0 = cosT[s * 32 + j0],      s0 = sinT[s * 32 + j0];
        const float c1 = cosT[s * 32 + 16 + j0], s1 = sinT[s * 32 + 16 + j0];
        qo[ob + j0]      = f2bf((acc[m][0][r] * c0 - acc[m][2][r] * s0) * QSCALE);
        qo[ob + 16 + j0] = f2bf((acc[m][1][r] * c1 - acc[m][3][r] * s1) * QSCALE);
        qo[ob + 32 + j0] = f2bf((acc[m][2][r] * c0 + acc[m][0][r] * s0) * QSCALE);
        qo[ob + 48 + j0] = f2bf((acc[m][3][r] * c1 + acc[m][1][r] * s1) * QSCALE);
      }
    }
  } else if (colBase < 1280) {                // ---- K: rope ----
    const int kvh2 = (colBase - 1024) >> 6;
#pragma unroll
    for (int m = 0; m < 4; ++m) {
      const int grow = (int)arow0 + wr * 64 + m * 16 + g * 4;
#pragma unroll
      for (int r = 0; r < 4; ++r) {
        const int row = grow + r;
        const int s = row & 2047, bb = row >> 11;
        const long ob = (((long)(bb * 4 + kvh2)) * 2048 + s) * 64;
        const float c0 = cosT[s * 32 + j0],      s0 = sinT[s * 32 + j0];
        const float c1 = cosT[s * 32 + 16 + j0], s1 = sinT[s * 32 + 16 + j0];
        ko[ob + j0]      = f2bf(acc[m][0][r] * c0 - acc[m][2][r] * s0);
        ko[ob + 16 + j0] = f2bf(acc[m][1][r] * c1 - acc[m][3][r] * s1);
        ko[ob + 32 + j0] = f2bf(acc[m][2][r] * c0 + acc[m][0][r] * s0);
        ko[ob + 48 + j0] = f2bf(acc[m][3][r] * c1 + acc[m][1][r] * s1);
      }
    }
  } else {                                    // ---- V (swapped acc): coalesced V^T store ----
    const int kvh2 = (colBase - 1280) >> 6;
    const int bb = (int)(arow0 >> 11);
    const int sBase = (int)(arow0 & 2047) + wr * 64;
    const long vrow0 = ((long)(bb * 4 + kvh2)) * 64;
#pragma unroll
    for (int mw = 0; mw < 4; ++mw) {          // W 16-row group (d)
      const int d0 = mw * 16 + g * 4;
#pragma unroll
      for (int r = 0; r < 4; ++r) {
        const long db = (vrow0 + d0 + r) * 2048;
#pragma unroll
        for (int nx = 0; nx < 4; ++nx)        // X 16-row group (s)
          vto[db + sBase + nx * 16 + l15] = f2bf(acc[mw][nx][r]);
      }
    }
  }
}

// ---------------- output projection GEMM (BK=64, dbuf, swizzled, XCD-chunked, fp32 out) ----------------
// flat grid 256: arowBlk=(bid&7)*4+((bid>>3)&3), wcolBlk=bid>>5 (0..7).

__global__ __launch_bounds__(256, 2) void gemm_out_kernel(
    const u16* __restrict__ A, const u16* __restrict__ W, float* __restrict__ Y) {
  const int K = 1024, N = 1024;
  __shared__ __align__(16) u16 As[2][128 * 64];
  __shared__ __align__(16) u16 Bs[2][128 * 64];
  const int tid = threadIdx.x;
  const int lane = tid & 63;
  const int wave = tid >> 6;
  const int g = lane >> 4, l15 = lane & 15;
  const int wr = wave >> 1, wc = wave & 1;
  const int bid = blockIdx.x;
  const int arowBlk = (bid & 7) * 4 + ((bid >> 3) & 3);
  const int wcolBlk = bid >> 5;
  const long arow0 = (long)arowBlk * 128;
  const long wrow0 = (long)wcolBlk * 128;
  const u16* Ab = A + arow0 * K;
  const u16* Wb = W + wrow0 * K;

  auto STAGE = [&](int buf, int k0) {
#pragma unroll
    for (int i = 0; i < 4; ++i) {
      const int lbase = i * 256 + wave * 64;
      const int c = lbase + lane;
      const int r = c >> 3, c8 = c & 7;
      const int cs = (c8 ^ (r & 7)) * 8;
      g2l16(Ab + (long)r * K + k0 + cs, (char*)As[buf] + lbase * 16);
      g2l16(Wb + (long)r * K + k0 + cs, (char*)Bs[buf] + lbase * 16);
    }
  };

  f32x4 acc[4][4] = {};
  int cur = 0;
  STAGE(0, 0);

  for (int k0 = 0; k0 < K; k0 += 64) {
    if (k0 + 64 < K) {
      STAGE(cur ^ 1, k0 + 64);
      asm volatile("s_waitcnt vmcnt(8)" ::: "memory");
    } else {
      asm volatile("s_waitcnt vmcnt(0)" ::: "memory");
    }
    __builtin_amdgcn_s_barrier();
#pragma unroll
    for (int ks = 0; ks < 2; ++ks) {
      s16x8 af[4], bfr[4];
#pragma unroll
      for (int m = 0; m < 4; ++m) {
        const int row = wr * 64 + m * 16 + l15;
        af[m] = *(const s16x8*)((const char*)As[cur] + row * 128 + (((ks * 4 + g) ^ (row & 7)) << 4));
      }
#pragma unroll
      for (int n = 0; n < 4; ++n) {
        const int row = wc * 64 + n * 16 + l15;
        bfr[n] = *(const s16x8*)((const char*)Bs[cur] + row * 128 + (((ks * 4 + g) ^ (row & 7)) << 4));
      }
      __builtin_amdgcn_s_setprio(1);
#pragma unroll
      for (int m = 0; m < 4; ++m)
#pragma unroll
        for (int n = 0; n < 4; ++n)
          acc[m][n] = __builtin_amdgcn_mfma_f32_16x16x32_bf16(af[m], bfr[n], acc[m][n], 0, 0, 0);
      __builtin_amdgcn_s_setprio(0);
    }
    __builtin_amdgcn_s_barrier();
    cur ^= 1;
  }

#pragma unroll
  for (int m = 0; m < 4; ++m)
#pragma unroll
    for (int n = 0; n < 4; ++n) {
      const long gr0 = arow0 + wr * 64 + m * 16 + g * 4;
      const long gc = wrow0 + wc * 64 + n * 16 + l15;
#pragma unroll
      for (int r = 0; r < 4; ++r)
        Y[(gr0 + r) * N + gc] = acc[m][n][r];
    }
}

// ---------------- flash attention (swapped QK^T, double-buffered, defer-max) ----------------
// grid 1024 flat; block handles ONE q-tile. XCD-chunked: xcd = bid&7 owns one (b,kvh)
// (K+V 512KB L2-resident); within an XCD, qt order 0,31,1,30,... so consecutive
// same-CU blocks alternate heavy/light. 3 blocks/CU (LDS 41KB) for VALU/MFMA overlap.

__global__ __launch_bounds__(256, 3) void flash_kernel(
    const u16* __restrict__ qg,   // [B][16][S][64]
    const u16* __restrict__ kg,   // [B][4][S][64]
    const u16* __restrict__ vtg,  // [B][4][64][S]
    u16* __restrict__ og) {       // [B][S][1024]
  const int tid = threadIdx.x, lane = tid & 63, w = tid >> 6;
  const int g = lane >> 4, l15 = lane & 15;

  const int bid = blockIdx.x;                  // 0..1023
  const int lid = (bid & 7) * 128 + (bid >> 3);
  const int qtIdx = lid & 31;
  const int h = (lid >> 5) & 15;
  const int b = lid >> 9;
  const int qt = (qtIdx & 1) ? (31 - (qtIdx >> 1)) : (qtIdx >> 1);
  const int kvh = h >> 2;

  __shared__ __align__(16) u16 Kl[2][64 * 64];   // [kv][d], 16B-XOR swizzled
  __shared__ __align__(16) u16 Vl[2][64 * 64];   // [d][kv], 16B-XOR swizzled
  __shared__ __align__(16) u16 Pl[4][16][72];    // per-wave P^T [q][kv], +8 pad

  const u16* Kp = kg  + ((long)(b * 4 + kvh)) * 2048 * 64;
  const u16* Vp = vtg + ((long)(b * 4 + kvh)) * 64 * 2048;

  auto STAGE = [&](int buf, int kt) {
#pragma unroll
    for (int j = 0; j < 2; ++j) {
      const int lbase = j * 256 + w * 64;          // wave-uniform chunk base
      const int c = lbase + lane;
      const int row = c >> 3, c8 = c & 7;
      const int cs = (c8 ^ (row & 7)) * 8;         // inverse-swizzled source (rule #21)
      g2l16(Kp + ((long)(kt * 64 + row)) * 64 + cs, (char*)Kl[buf] + lbase * 16);
      g2l16(Vp + (long)row * 2048 + kt * 64 + cs,  (char*)Vl[buf] + lbase * 16);
    }
  };

  const u16* Qp = qg + (((long)(b * 16 + h)) * 2048 + qt * 64 + w * 16) * 64;
  const s16x8 qf0 = *(const s16x8*)(Qp + l15 * 64 + g * 8);
  const s16x8 qf1 = *(const s16x8*)(Qp + l15 * 64 + 32 + g * 8);

  f32x4 of[4] = {};
  float m = -1e30f, lsum = 0.f;
  const int qrow = qt * 64 + w * 16 + l15;

  int cur = 0;
  STAGE(0, 0);

#pragma unroll 1
  for (int kt = 0; kt <= qt; ++kt) {
    if (kt < qt) {
      STAGE(cur ^ 1, kt + 1);
      asm volatile("s_waitcnt vmcnt(4)" ::: "memory");   // cur's 4 loads done; next 4 in flight
    } else {
      asm volatile("s_waitcnt vmcnt(0)" ::: "memory");
    }
    __builtin_amdgcn_s_barrier();
    const u16* Kb = Kl[cur];
    const u16* Vb = Vl[cur];

    // S^T tile: mfma(K, Q) -> C[kv][q], lane owns q = l15, 16 kv values in regs
    f32x4 sf[4] = {};
    __builtin_amdgcn_s_setprio(1);
#pragma unroll
    for (int ks = 0; ks < 2; ++ks) {
      const s16x8 qv = ks ? qf1 : qf0;
#pragma unroll
      for (int fn = 0; fn < 4; ++fn) {
        const int row = fn * 16 + l15;
        const s16x8 kf = *(const s16x8*)((const char*)Kb + row * 128 + (((ks * 4 + g) ^ (row & 7)) << 4));
        sf[fn] = __builtin_amdgcn_mfma_f32_16x16x32_bf16(kf, qv, sf[fn], 0, 0, 0);
      }
    }
    __builtin_amdgcn_s_setprio(0);

    // causal mask; row max via max3-friendly triples (+2 shuffles)
    const bool diag = (kt == qt);
    float p[16];
#pragma unroll
    for (int fn = 0; fn < 4; ++fn)
#pragma unroll
      for (int r = 0; r < 4; ++r) {
        float sv = sf[fn][r];
        if (diag) {
          const int kv = kt * 64 + fn * 16 + 4 * g + r;
          if (kv > qrow) sv = -1e30f;
        }
        p[fn * 4 + r] = sv;
      }
    const float t0 = fmaxf(fmaxf(p[0], p[1]), p[2]);
    const float t1 = fmaxf(fmaxf(p[3], p[4]), p[5]);
    const float t2 = fmaxf(fmaxf(p[6], p[7]), p[8]);
    const float t3 = fmaxf(fmaxf(p[9], p[10]), p[11]);
    const float t4 = fmaxf(fmaxf(p[12], p[13]), p[14]);
    float mx = fmaxf(fmaxf(fmaxf(t0, t1), t2), fmaxf(fmaxf(t3, t4), p[15]));
    mx = fmaxf(mx, __shfl_xor(mx, 16));
    mx = fmaxf(mx, __shfl_xor(mx, 32));

    // defer-max (T13): rescale only when max grew by > 11 (base-2)
    if (!__all(mx - m <= 11.0f)) {
      const float mn = fmaxf(m, mx);
      const float al = exp2fast(m - mn);
      m = mn;
      lsum *= al;
      float alq[4];
#pragma unroll
      for (int r = 0; r < 4; ++r) alq[r] = __shfl(al, 4 * g + r);
#pragma unroll
      for (int fd = 0; fd < 4; ++fd)
#pragma unroll
        for (int r = 0; r < 4; ++r) of[fd][r] *= alq[r];
    }

#pragma unroll
    for (int i = 0; i < 16; ++i) p[i] = exp2fast(p[i] - m);
    const float s0 = (p[0] + p[1]) + (p[2] + p[3]);
    const float s1 = (p[4] + p[5]) + (p[6] + p[7]);
    const float s2 = (p[8] + p[9]) + (p[10] + p[11]);
    const float s3 = (p[12] + p[13]) + (p[14] + p[15]);
    float rs = (s0 + s1) + (s2 + s3);
    rs += __shfl_xor(rs, 16);
    rs += __shfl_xor(rs, 32);
    lsum += rs;

    // P^T -> padded LDS [q][kv] via v_cvt_pk_bf16_f32 (4 b64 writes)
    u16* Pw = &Pl[w][l15][0];
#pragma unroll
    for (int fn = 0; fn < 4; ++fn) {
      const u32x2 v2 = {cvt_pk(p[fn * 4 + 0], p[fn * 4 + 1]),
                        cvt_pk(p[fn * 4 + 2], p[fn * 4 + 3])};
      *(u32x2*)(Pw + fn * 16 + g * 4) = v2;    // kv = fn*16 + 4g
    }

    // O += P @ V : A-frag = P rows (q), B-frag = V^T rows (d)
    __builtin_amdgcn_s_setprio(1);
#pragma unroll
    for (int ks = 0; ks < 2; ++ks) {
      const s16x8 pa = *(const s16x8*)(&Pl[w][l15][ks * 32 + g * 8]);
#pragma unroll
      for (int fd = 0; fd < 4; ++fd) {
        const int vrow = fd * 16 + l15;
        const s16x8 vf = *(const s16x8*)((const char*)Vb + vrow * 128 + (((ks * 4 + g) ^ (vrow & 7)) << 4));
        of[fd] = __builtin_amdgcn_mfma_f32_16x16x32_bf16(pa, vf, of[fd], 0, 0, 0);
      }
    }
    __builtin_amdgcn_s_setprio(0);

    __builtin_amdgcn_s_barrier();   // all waves done reading cur before it's restaged
    cur ^= 1;
  }

  // normalize + store; of rows are q_local = 4g+r, stats live at lane 4g+r
  float linv[4];
#pragma unroll
  for (int r = 0; r < 4; ++r) linv[r] = 1.0f / __shfl(lsum, 4 * g + r);
  const long orow0 = (long)b * 2048 + qt * 64 + w * 16 + 4 * g;
#pragma unroll
  for (int r = 0; r < 4; ++r) {
    const long gb = (orow0 + r) * 1024 + h * 64;
#pragma unroll
    for (int fd = 0; fd < 4; ++fd)
      og[gb + fd * 16 + l15] = f2bf(of[fd][r] * linv[r]);
  }
}

// ---------------- launch ----------------

extern "C" void kernel_launch(void* const* d_in, const int* in_sizes, int n_in,
                              void* d_out, int out_size, void* d_ws, size_t ws_size,
                              hipStream_t stream) {
  (void)in_sizes; (void)n_in; (void)out_size; (void)ws_size;
  const float* x  = (const float*)d_in[0];
  const float* wq = (const float*)d_in[1];
  const float* wk = (const float*)d_in[2];
  const float* wv = (const float*)d_in[3];
  const float* wo = (const float*)d_in[4];
  float* out = (float*)d_out;

  char* p = (char*)d_ws;
  auto alloc = [&](size_t bytes) { char* r = p; p += (bytes + 255) & ~(size_t)255; return r; };

  u16* xb    = (u16*)alloc(4096ull * 1024 * 2);
  u16* wcat  = (u16*)alloc(1536ull * 1024 * 2);   // [wq; wk; wv]
  u16* wob   = (u16*)alloc(1024ull * 1024 * 2);
  u16* qrb   = (u16*)alloc(4096ull * 1024 * 2);   // [B][16][S][64]
  u16* krb   = (u16*)alloc(4096ull * 256 * 2);    // [B][4][S][64]
  u16* vtb   = (u16*)alloc(4096ull * 256 * 2);    // [B][4][64][S]
  u16* aob   = (u16*)alloc(4096ull * 1024 * 2);   // [B][S][1024]
  float* cosT = (float*)alloc(2048ull * 32 * 4);
  float* sinT = (float*)alloc(2048ull * 32 * 4);

  // single fused prep: weight/x conversions + trig tables
  prep_kernel<<<6720, 256, 0, stream>>>(x, wq, wk, wv, wo, xb, wcat, wob, cosT, sinT);

  // fused QKV projection + rope + layout (XCD-chunked flat grid)
  gemm_qkv_kernel<<<384, 256, 0, stream>>>(xb, wcat, qrb, krb, vtb, cosT, sinT);

  // causal GQA flash attention (one q-tile per block, XCD-chunked)
  flash_kernel<<<1024, 256, 0, stream>>>(qrb, krb, vtb, aob);

  // output projection (fp32 out, XCD-chunked flat grid)
  gemm_out_kernel<<<256, 256, 0, stream>>>(aob, wob, out);
}

// Round 9
// 187.171 us; speedup vs baseline: 1.0363x; 1.0363x over previous
//
#include <hip/hip_runtime.h>
#include <stdint.h>

typedef unsigned short u16;
typedef __attribute__((ext_vector_type(8))) short s16x8;   // bf16x8 MFMA frag (4 VGPRs)
typedef __attribute__((ext_vector_type(4))) float f32x4;   // MFMA C/D frag
typedef __attribute__((ext_vector_type(4))) unsigned short u16x4;
typedef __attribute__((ext_vector_type(2))) unsigned int u32x2;

// ---------------- helpers ----------------

__device__ __forceinline__ u16 f2bf(float f) {
  unsigned u = __float_as_uint(f);
  unsigned r = (u + 0x7fffu + ((u >> 16) & 1u)) >> 16;   // RNE
  return (u16)r;
}
__device__ __forceinline__ unsigned cvt_pk(float lo, float hi) {
  unsigned r;
  asm("v_cvt_pk_bf16_f32 %0, %1, %2" : "=v"(r) : "v"(lo), "v"(hi));
  return r;
}
__device__ __forceinline__ float exp2fast(float x) {
  return __builtin_amdgcn_exp2f(x);   // v_exp_f32: D = 2^S0
}

typedef const __attribute__((address_space(1))) unsigned int* gas_ptr;
typedef __attribute__((address_space(3))) unsigned int* las_ptr;

__device__ __forceinline__ void g2l16(const void* g, void* l) {
  __builtin_amdgcn_global_load_lds((gas_ptr)g, (las_ptr)l, 16, 0, 0);
}

__device__ __forceinline__ void cvt4(const float* __restrict__ in, u16* __restrict__ out) {
  const f32x4 v = *(const f32x4*)in;
  u16x4 o;
  o[0] = f2bf(v[0]); o[1] = f2bf(v[1]); o[2] = f2bf(v[2]); o[3] = f2bf(v[3]);
  *(u16x4*)out = o;
}

// ---------------- fused prep: all bf16 conversions + trig tables ----------------

__global__ void prep_kernel(const float* __restrict__ x,  const float* __restrict__ wq,
                            const float* __restrict__ wk, const float* __restrict__ wv,
                            const float* __restrict__ wo,
                            u16* __restrict__ xb, u16* __restrict__ wcat, u16* __restrict__ wob,
                            float* __restrict__ cosT, float* __restrict__ sinT) {
  const long id = (long)blockIdx.x * 256 + threadIdx.x;
  if (id < 262144) {                       // wq -> wcat rows 0..1023
    cvt4(wq + id * 4, wcat + id * 4);
  } else if (id < 327680) {                // wk -> wcat rows 1024..1279
    const long i = id - 262144;
    cvt4(wk + i * 4, wcat + 1048576 + i * 4);
  } else if (id < 393216) {                // wv -> wcat rows 1280..1535
    const long i = id - 327680;
    cvt4(wv + i * 4, wcat + 1310720 + i * 4);
  } else if (id < 655360) {                // wo
    const long i = id - 393216;
    cvt4(wo + i * 4, wob + i * 4);
  } else if (id < 671744) {                // trig tables, 4 entries per id
    const long t = id - 655360;
#pragma unroll
    for (int u = 0; u < 4; ++u) {
      const long idx = t * 4 + u;
      const int s = (int)(idx >> 5), j = (int)(idx & 31);
      const double invd = exp(-(double)j * 0.2878231366242558);  // ln(10000)/32
      const float a = (float)s * (float)invd;
      cosT[idx] = cosf(a);
      sinT[idx] = sinf(a);
    }
  } else {                                 // x
    const long i = id - 671744;
    cvt4(x + i * 4, xb + i * 4);
  }
}

// ---------------- fused QKV projection GEMM (BK=32, 4-stage pipeline, swizzled) ----------------
// flat grid 384 (XCD-chunked). V blocks (wcolBlk >= 10) swap MFMA operands ->
// transposed acc -> coalesced V^T store.

__global__ __launch_bounds__(256, 2) void gemm_qkv_kernel(
    const u16* __restrict__ A, const u16* __restrict__ W,
    u16* __restrict__ qo, u16* __restrict__ ko, u16* __restrict__ vto,
    const float* __restrict__ cosT, const float* __restrict__ sinT) {
  const int K = 1024;
  __shared__ __align__(16) u16 As[4][128 * 32];
  __shared__ __align__(16) u16 Bs[4][128 * 32];
  const int tid = threadIdx.x;
  const int lane = tid & 63;
  const int wave = tid >> 6;
  const int g = lane >> 4, l15 = lane & 15;
  const int wr = wave >> 1, wc = wave & 1;
  const int bid = blockIdx.x;
  const int arowBlk = (bid & 7) * 4 + ((bid >> 3) & 3);
  const int wcolBlk = bid >> 5;
  const long arow0 = (long)arowBlk * 128;
  const long wrow0 = (long)wcolBlk * 128;
  const u16* Ab = A + arow0 * K;
  const u16* Wb = W + wrow0 * K;
  const bool isV = (wcolBlk >= 10);

  auto STAGE = [&](int buf, int k0) {
#pragma unroll
    for (int j = 0; j < 2; ++j) {
      const int lbase = j * 256 + wave * 64;
      const int c = lbase + lane;
      const int r = c >> 2, c4 = c & 3;
      const int cs = (c4 ^ ((r >> 1) & 3)) * 8;   // inverse-swizzled source (rule #21)
      g2l16(Ab + (long)r * K + k0 + cs, (char*)As[buf] + lbase * 16);
      g2l16(Wb + (long)r * K + k0 + cs, (char*)Bs[buf] + lbase * 16);
    }
  };

  f32x4 acc[4][4] = {};
  STAGE(0, 0); STAGE(1, 32); STAGE(2, 64);

#pragma unroll 1
  for (int t = 0; t < 32; ++t) {
    if (t < 29) {
      STAGE((t + 3) & 3, (t + 3) * 32);
      asm volatile("s_waitcnt vmcnt(12)" ::: "memory");   // stage t done; 3 ahead in flight
    } else if (t == 29) {
      asm volatile("s_waitcnt vmcnt(8)" ::: "memory");
    } else if (t == 30) {
      asm volatile("s_waitcnt vmcnt(4)" ::: "memory");
    } else {
      asm volatile("s_waitcnt vmcnt(0)" ::: "memory");
    }
    __builtin_amdgcn_s_barrier();
    const u16* Ac = As[t & 3];
    const u16* Bc = Bs[t & 3];
    s16x8 af[4], bfr[4];
#pragma unroll
    for (int m = 0; m < 4; ++m) {
      const int row = wr * 64 + m * 16 + l15;
      af[m] = *(const s16x8*)((const char*)Ac + row * 64 + ((g ^ ((row >> 1) & 3)) << 4));
    }
#pragma unroll
    for (int n = 0; n < 4; ++n) {
      const int row = wc * 64 + n * 16 + l15;
      bfr[n] = *(const s16x8*)((const char*)Bc + row * 64 + ((g ^ ((row >> 1) & 3)) << 4));
    }
    __builtin_amdgcn_s_setprio(1);
    if (!isV) {
#pragma unroll
      for (int m = 0; m < 4; ++m)
#pragma unroll
        for (int n = 0; n < 4; ++n)
          acc[m][n] = __builtin_amdgcn_mfma_f32_16x16x32_bf16(af[m], bfr[n], acc[m][n], 0, 0, 0);
    } else {
#pragma unroll
      for (int m = 0; m < 4; ++m)
#pragma unroll
        for (int n = 0; n < 4; ++n)
          acc[m][n] = __builtin_amdgcn_mfma_f32_16x16x32_bf16(bfr[m], af[n], acc[m][n], 0, 0, 0);
    }
    __builtin_amdgcn_s_setprio(0);
    __builtin_amdgcn_s_barrier();
  }

  const int colBase = (int)wrow0 + wc * 64;
  const int j0 = l15;
  const float QSCALE = 0.18033688011112042f;   // 0.125 * log2(e): softmax done in base 2

  if (colBase < 1024) {                       // ---- Q: rope + scale ----
    const int h2 = colBase >> 6;
#pragma unroll
    for (int m = 0; m < 4; ++m) {
      const int grow = (int)arow0 + wr * 64 + m * 16 + g * 4;
#pragma unroll
      for (int r = 0; r < 4; ++r) {
        const int row = grow + r;
        const int s = row & 2047, bb = row >> 11;
        const long ob = (((long)(bb * 16 + h2)) * 2048 + s) * 64;
        const float c0 = cosT[s * 32 + j0],      s0 = sinT[s * 32 + j0];
        const float c1 = cosT[s * 32 + 16 + j0], s1 = sinT[s * 32 + 16 + j0];
        qo[ob + j0]      = f2bf((acc[m][0][r] * c0 - acc[m][2][r] * s0) * QSCALE);
        qo[ob + 16 + j0] = f2bf((acc[m][1][r] * c1 - acc[m][3][r] * s1) * QSCALE);
        qo[ob + 32 + j0] = f2bf((acc[m][2][r] * c0 + acc[m][0][r] * s0) * QSCALE);
        qo[ob + 48 + j0] = f2bf((acc[m][3][r] * c1 + acc[m][1][r] * s1) * QSCALE);
      }
    }
  } else if (colBase < 1280) {                // ---- K: rope ----
    const int kvh2 = (colBase - 1024) >> 6;
#pragma unroll
    for (int m = 0; m < 4; ++m) {
      const int grow = (int)arow0 + wr * 64 + m * 16 + g * 4;
#pragma unroll
      for (int r = 0; r < 4; ++r) {
        const int row = grow + r;
        const int s = row & 2047, bb = row >> 11;
        const long ob = (((long)(bb * 4 + kvh2)) * 2048 + s) * 64;
        const float c0 = cosT[s * 32 + j0],      s0 = sinT[s * 32 + j0];
        const float c1 = cosT[s * 32 + 16 + j0], s1 = sinT[s * 32 + 16 + j0];
        ko[ob + j0]      = f2bf(acc[m][0][r] * c0 - acc[m][2][r] * s0);
        ko[ob + 16 + j0] = f2bf(acc[m][1][r] * c1 - acc[m][3][r] * s1);
        ko[ob + 32 + j0] = f2bf(acc[m][2][r] * c0 + acc[m][0][r] * s0);
        ko[ob + 48 + j0] = f2bf(acc[m][3][r] * c1 + acc[m][1][r] * s1);
      }
    }
  } else {                                    // ---- V (swapped acc): coalesced V^T store ----
    const int kvh2 = (colBase - 1280) >> 6;
    const int bb = (int)(arow0 >> 11);
    const int sBase = (int)(arow0 & 2047) + wr * 64;
    const long vrow0 = ((long)(bb * 4 + kvh2)) * 64;
#pragma unroll
    for (int mw = 0; mw < 4; ++mw) {          // W 16-row group (d)
      const int d0 = mw * 16 + g * 4;
#pragma unroll
      for (int r = 0; r < 4; ++r) {
        const long db = (vrow0 + d0 + r) * 2048;
#pragma unroll
        for (int nx = 0; nx < 4; ++nx)        // X 16-row group (s)
          vto[db + sBase + nx * 16 + l15] = f2bf(acc[mw][nx][r]);
      }
    }
  }
}

// ---------------- output projection GEMM (BK=32, 4-stage pipeline, fp32 out) ----------------

__global__ __launch_bounds__(256, 2) void gemm_out_kernel(
    const u16* __restrict__ A, const u16* __restrict__ W, float* __restrict__ Y) {
  const int K = 1024, N = 1024;
  __shared__ __align__(16) u16 As[4][128 * 32];
  __shared__ __align__(16) u16 Bs[4][128 * 32];
  const int tid = threadIdx.x;
  const int lane = tid & 63;
  const int wave = tid >> 6;
  const int g = lane >> 4, l15 = lane & 15;
  const int wr = wave >> 1, wc = wave & 1;
  const int bid = blockIdx.x;
  const int arowBlk = (bid & 7) * 4 + ((bid >> 3) & 3);
  const int wcolBlk = bid >> 5;
  const long arow0 = (long)arowBlk * 128;
  const long wrow0 = (long)wcolBlk * 128;
  const u16* Ab = A + arow0 * K;
  const u16* Wb = W + wrow0 * K;

  auto STAGE = [&](int buf, int k0) {
#pragma unroll
    for (int j = 0; j < 2; ++j) {
      const int lbase = j * 256 + wave * 64;
      const int c = lbase + lane;
      const int r = c >> 2, c4 = c & 3;
      const int cs = (c4 ^ ((r >> 1) & 3)) * 8;
      g2l16(Ab + (long)r * K + k0 + cs, (char*)As[buf] + lbase * 16);
      g2l16(Wb + (long)r * K + k0 + cs, (char*)Bs[buf] + lbase * 16);
    }
  };

  f32x4 acc[4][4] = {};
  STAGE(0, 0); STAGE(1, 32); STAGE(2, 64);

#pragma unroll 1
  for (int t = 0; t < 32; ++t) {
    if (t < 29) {
      STAGE((t + 3) & 3, (t + 3) * 32);
      asm volatile("s_waitcnt vmcnt(12)" ::: "memory");
    } else if (t == 29) {
      asm volatile("s_waitcnt vmcnt(8)" ::: "memory");
    } else if (t == 30) {
      asm volatile("s_waitcnt vmcnt(4)" ::: "memory");
    } else {
      asm volatile("s_waitcnt vmcnt(0)" ::: "memory");
    }
    __builtin_amdgcn_s_barrier();
    const u16* Ac = As[t & 3];
    const u16* Bc = Bs[t & 3];
    s16x8 af[4], bfr[4];
#pragma unroll
    for (int m = 0; m < 4; ++m) {
      const int row = wr * 64 + m * 16 + l15;
      af[m] = *(const s16x8*)((const char*)Ac + row * 64 + ((g ^ ((row >> 1) & 3)) << 4));
    }
#pragma unroll
    for (int n = 0; n < 4; ++n) {
      const int row = wc * 64 + n * 16 + l15;
      bfr[n] = *(const s16x8*)((const char*)Bc + row * 64 + ((g ^ ((row >> 1) & 3)) << 4));
    }
    __builtin_amdgcn_s_setprio(1);
#pragma unroll
    for (int m = 0; m < 4; ++m)
#pragma unroll
      for (int n = 0; n < 4; ++n)
        acc[m][n] = __builtin_amdgcn_mfma_f32_16x16x32_bf16(af[m], bfr[n], acc[m][n], 0, 0, 0);
    __builtin_amdgcn_s_setprio(0);
    __builtin_amdgcn_s_barrier();
  }

#pragma unroll
  for (int m = 0; m < 4; ++m)
#pragma unroll
    for (int n = 0; n < 4; ++n) {
      const long gr0 = arow0 + wr * 64 + m * 16 + g * 4;
      const long gc = wrow0 + wc * 64 + n * 16 + l15;
#pragma unroll
      for (int r = 0; r < 4; ++r)
        Y[(gr0 + r) * N + gc] = acc[m][n][r];
    }
}

// ---------------- flash attention (paired blocks, KVBLK=128, swapped QK^T, defer-max) ----------------
// grid 512 flat (XCD-chunked remap); block does q-tiles pr and 31-pr (balanced, 33 kv-tiles).
// KV staged 128 rows per stage -> barriers/shuffles/waits halved vs KVBLK=64.

__global__ __launch_bounds__(256, 2) void flash_kernel(
    const u16* __restrict__ qg,   // [B][16][S][64]
    const u16* __restrict__ kg,   // [B][4][S][64]
    const u16* __restrict__ vtg,  // [B][4][64][S]
    u16* __restrict__ og) {       // [B][S][1024]
  const int tid = threadIdx.x, lane = tid & 63, w = tid >> 6;
  const int g = lane >> 4, l15 = lane & 15;

  const int bid = blockIdx.x;
  const int lid = (bid & 7) * 64 + (bid >> 3);
  const int pr = lid & 15, h = (lid >> 4) & 15, b = lid >> 8;
  const int kvh = h >> 2;

  __shared__ __align__(16) u16 Kl[2][128 * 64];  // [kv][d], 8-chunk XOR swizzle
  __shared__ __align__(16) u16 Vl[2][64 * 128];  // [d][kv], 16-chunk XOR swizzle (low 3 bits)
  __shared__ __align__(16) u16 Pl[4][16][76];    // per-wave P [q][kv64], +12 pad, reused 2x/stage

  const u16* Kp = kg  + ((long)(b * 4 + kvh)) * 2048 * 64;
  const u16* Vp = vtg + ((long)(b * 4 + kvh)) * 64 * 2048;

  auto STAGE = [&](int buf, int st) {
#pragma unroll
    for (int j = 0; j < 4; ++j) {
      const int lbase = j * 256 + w * 64;          // wave-uniform chunk base
      const int c = lbase + lane;
      {
        const int row = c >> 3, c8 = c & 7;
        const int cs = (c8 ^ (row & 7)) * 8;       // inverse-swizzled source (rule #21)
        g2l16(Kp + ((long)(st * 128 + row)) * 64 + cs, (char*)Kl[buf] + lbase * 16);
      }
      {
        const int row = c >> 4, c16 = c & 15;
        const int cs = (c16 ^ (row & 7)) * 8;
        g2l16(Vp + (long)row * 2048 + st * 128 + cs, (char*)Vl[buf] + lbase * 16);
      }
    }
  };

#pragma unroll 1
  for (int pass = 0; pass < 2; ++pass) {
    const int qt = pass ? (31 - pr) : pr;
    const int nst = (qt + 2) >> 1;               // 128-wide kv stages
    const u16* Qp = qg + (((long)(b * 16 + h)) * 2048 + qt * 64 + w * 16) * 64;
    const s16x8 qf0 = *(const s16x8*)(Qp + l15 * 64 + g * 8);
    const s16x8 qf1 = *(const s16x8*)(Qp + l15 * 64 + 32 + g * 8);

    f32x4 of[4] = {};
    float m = -1e30f, lsum = 0.f;
    const int qrow = qt * 64 + w * 16 + l15;

    int cur = 0;
    STAGE(0, 0);

#pragma unroll 1
    for (int st = 0; st < nst; ++st) {
      if (st + 1 < nst) {
        STAGE(cur ^ 1, st + 1);
        asm volatile("s_waitcnt vmcnt(8)" ::: "memory");   // cur's 8 loads done
      } else {
        asm volatile("s_waitcnt vmcnt(0)" ::: "memory");
      }
      __builtin_amdgcn_s_barrier();
      const u16* Kb = Kl[cur];
      const u16* Vb = Vl[cur];

      // S^T: mfma(K, Q) -> C[kv][q]; lane owns q=l15, 32 kv values in regs
      f32x4 sf[8] = {};
      __builtin_amdgcn_s_setprio(1);
#pragma unroll
      for (int ks = 0; ks < 2; ++ks) {
        const s16x8 qv = ks ? qf1 : qf0;
#pragma unroll
        for (int fn = 0; fn < 8; ++fn) {
          const int row = fn * 16 + l15;
          const s16x8 kf = *(const s16x8*)((const char*)Kb + row * 128 + (((ks * 4 + g) ^ (row & 7)) << 4));
          sf[fn] = __builtin_amdgcn_mfma_f32_16x16x32_bf16(kf, qv, sf[fn], 0, 0, 0);
        }
      }
      __builtin_amdgcn_s_setprio(0);

      // causal mask (only last stage can cross the diagonal)
      const bool diag = (st == nst - 1);
      float p[32];
#pragma unroll
      for (int fn = 0; fn < 8; ++fn)
#pragma unroll
        for (int r = 0; r < 4; ++r) {
          float sv = sf[fn][r];
          if (diag) {
            const int kv = st * 128 + fn * 16 + 4 * g + r;
            if (kv > qrow) sv = -1e30f;
          }
          p[fn * 4 + r] = sv;
        }

      // row max: 5-level tree + 2 shuffles
      float t16[16];
#pragma unroll
      for (int i = 0; i < 16; ++i) t16[i] = fmaxf(p[i], p[i + 16]);
#pragma unroll
      for (int i = 0; i < 8; ++i) t16[i] = fmaxf(t16[i], t16[i + 8]);
#pragma unroll
      for (int i = 0; i < 4; ++i) t16[i] = fmaxf(t16[i], t16[i + 4]);
      float mx = fmaxf(fmaxf(t16[0], t16[1]), fmaxf(t16[2], t16[3]));
      mx = fmaxf(mx, __shfl_xor(mx, 16));
      mx = fmaxf(mx, __shfl_xor(mx, 32));

      // defer-max (T13): rescale only when max grew by > 11 (base-2)
      if (!__all(mx - m <= 11.0f)) {
        const float mn = fmaxf(m, mx);
        const float al = exp2fast(m - mn);
        m = mn;
        lsum *= al;
        float alq[4];
#pragma unroll
        for (int r = 0; r < 4; ++r) alq[r] = __shfl(al, 4 * g + r);
#pragma unroll
        for (int fd = 0; fd < 4; ++fd)
#pragma unroll
          for (int r = 0; r < 4; ++r) of[fd][r] *= alq[r];
      }

#pragma unroll
      for (int i = 0; i < 32; ++i) p[i] = exp2fast(p[i] - m);
      float s8[8];
#pragma unroll
      for (int i = 0; i < 8; ++i) s8[i] = (p[i * 4] + p[i * 4 + 1]) + (p[i * 4 + 2] + p[i * 4 + 3]);
      float rs = ((s8[0] + s8[1]) + (s8[2] + s8[3])) + ((s8[4] + s8[5]) + (s8[6] + s8[7]));
      rs += __shfl_xor(rs, 16);
      rs += __shfl_xor(rs, 32);
      lsum += rs;

      u16* Pw = &Pl[w][l15][0];

      // ---- half A: kv_local 0..63 ----
#pragma unroll
      for (int fn = 0; fn < 4; ++fn) {
        const u32x2 v2 = {cvt_pk(p[fn * 4 + 0], p[fn * 4 + 1]),
                          cvt_pk(p[fn * 4 + 2], p[fn * 4 + 3])};
        *(u32x2*)(Pw + fn * 16 + g * 4) = v2;
      }
      __builtin_amdgcn_s_setprio(1);
#pragma unroll
      for (int ks = 0; ks < 2; ++ks) {
        const s16x8 pa = *(const s16x8*)(Pw + ks * 32 + g * 8);
#pragma unroll
        for (int fd = 0; fd < 4; ++fd) {
          const int vrow = fd * 16 + l15;
          const s16x8 vf = *(const s16x8*)((const char*)Vb + vrow * 256 + (((ks * 4 + g) ^ (vrow & 7)) << 4));
          of[fd] = __builtin_amdgcn_mfma_f32_16x16x32_bf16(pa, vf, of[fd], 0, 0, 0);
        }
      }
      __builtin_amdgcn_s_setprio(0);

      // ---- half B: kv_local 64..127 (reuse Pl slots; same-wave DS ordering) ----
#pragma unroll
      for (int fn = 0; fn < 4; ++fn) {
        const u32x2 v2 = {cvt_pk(p[16 + fn * 4 + 0], p[16 + fn * 4 + 1]),
                          cvt_pk(p[16 + fn * 4 + 2], p[16 + fn * 4 + 3])};
        *(u32x2*)(Pw + fn * 16 + g * 4) = v2;
      }
      __builtin_amdgcn_s_setprio(1);
#pragma unroll
      for (int ks = 2; ks < 4; ++ks) {
        const s16x8 pa = *(const s16x8*)(Pw + (ks - 2) * 32 + g * 8);
#pragma unroll
        for (int fd = 0; fd < 4; ++fd) {
          const int vrow = fd * 16 + l15;
          const s16x8 vf = *(const s16x8*)((const char*)Vb + vrow * 256 + (((ks * 4 + g) ^ (vrow & 7)) << 4));
          of[fd] = __builtin_amdgcn_mfma_f32_16x16x32_bf16(pa, vf, of[fd], 0, 0, 0);
        }
      }
      __builtin_amdgcn_s_setprio(0);

      __builtin_amdgcn_s_barrier();   // all waves done reading cur before it's restaged
      cur ^= 1;
    }

    // normalize + store; of rows are q_local = 4g+r, stats live at lane 4g+r
    float linv[4];
#pragma unroll
    for (int r = 0; r < 4; ++r) linv[r] = 1.0f / __shfl(lsum, 4 * g + r);
    const long orow0 = (long)b * 2048 + qt * 64 + w * 16 + 4 * g;
#pragma unroll
    for (int r = 0; r < 4; ++r) {
      const long gb = (orow0 + r) * 1024 + h * 64;
#pragma unroll
      for (int fd = 0; fd < 4; ++fd)
        og[gb + fd * 16 + l15] = f2bf(of[fd][r] * linv[r]);
    }
  }
}

// ---------------- launch ----------------

extern "C" void kernel_launch(void* const* d_in, const int* in_sizes, int n_in,
                              void* d_out, int out_size, void* d_ws, size_t ws_size,
                              hipStream_t stream) {
  (void)in_sizes; (void)n_in; (void)out_size; (void)ws_size;
  const float* x  = (const float*)d_in[0];
  const float* wq = (const float*)d_in[1];
  const float* wk = (const float*)d_in[2];
  const float* wv = (const float*)d_in[3];
  const float* wo = (const float*)d_in[4];
  float* out = (float*)d_out;

  char* p = (char*)d_ws;
  auto alloc = [&](size_t bytes) { char* r = p; p += (bytes + 255) & ~(size_t)255; return r; };

  u16* xb    = (u16*)alloc(4096ull * 1024 * 2);
  u16* wcat  = (u16*)alloc(1536ull * 1024 * 2);   // [wq; wk; wv]
  u16* wob   = (u16*)alloc(1024ull * 1024 * 2);
  u16* qrb   = (u16*)alloc(4096ull * 1024 * 2);   // [B][16][S][64]
  u16* krb   = (u16*)alloc(4096ull * 256 * 2);    // [B][4][S][64]
  u16* vtb   = (u16*)alloc(4096ull * 256 * 2);    // [B][4][64][S]
  u16* aob   = (u16*)alloc(4096ull * 1024 * 2);   // [B][S][1024]
  float* cosT = (float*)alloc(2048ull * 32 * 4);
  float* sinT = (float*)alloc(2048ull * 32 * 4);

  // single fused prep: weight/x conversions + trig tables
  prep_kernel<<<6720, 256, 0, stream>>>(x, wq, wk, wv, wo, xb, wcat, wob, cosT, sinT);

  // fused QKV projection + rope + layout
  gemm_qkv_kernel<<<384, 256, 0, stream>>>(xb, wcat, qrb, krb, vtb, cosT, sinT);

  // causal GQA flash attention (balanced pairs, KVBLK=128)
  flash_kernel<<<512, 256, 0, stream>>>(qrb, krb, vtb, aob);

  // output projection (fp32 out)
  gemm_out_kernel<<<256, 256, 0, stream>>>(aob, wob, out);
}

// Round 10
// 166.867 us; speedup vs baseline: 1.1624x; 1.1217x over previous
//
#include <hip/hip_runtime.h>
#include <stdint.h>

typedef unsigned short u16;
typedef __attribute__((ext_vector_type(8))) short s16x8;   // bf16x8 MFMA frag (4 VGPRs)
typedef __attribute__((ext_vector_type(4))) float f32x4;   // MFMA C/D frag
typedef __attribute__((ext_vector_type(4))) unsigned short u16x4;
typedef __attribute__((ext_vector_type(2))) unsigned int u32x2;

// ---------------- helpers ----------------

__device__ __forceinline__ u16 f2bf(float f) {
  unsigned u = __float_as_uint(f);
  unsigned r = (u + 0x7fffu + ((u >> 16) & 1u)) >> 16;   // RNE
  return (u16)r;
}
__device__ __forceinline__ unsigned cvt_pk(float lo, float hi) {
  unsigned r;
  asm("v_cvt_pk_bf16_f32 %0, %1, %2" : "=v"(r) : "v"(lo), "v"(hi));
  return r;
}
__device__ __forceinline__ float exp2fast(float x) {
  return __builtin_amdgcn_exp2f(x);   // v_exp_f32: D = 2^S0
}

typedef const __attribute__((address_space(1))) unsigned int* gas_ptr;
typedef __attribute__((address_space(3))) unsigned int* las_ptr;

__device__ __forceinline__ void g2l16(const void* g, void* l) {
  __builtin_amdgcn_global_load_lds((gas_ptr)g, (las_ptr)l, 16, 0, 0);
}

__device__ __forceinline__ void cvt4(const float* __restrict__ in, u16* __restrict__ out) {
  const f32x4 v = *(const f32x4*)in;
  u16x4 o;
  o[0] = f2bf(v[0]); o[1] = f2bf(v[1]); o[2] = f2bf(v[2]); o[3] = f2bf(v[3]);
  *(u16x4*)out = o;
}

// ---------------- fused prep: all bf16 conversions + trig tables ----------------

__global__ void prep_kernel(const float* __restrict__ x,  const float* __restrict__ wq,
                            const float* __restrict__ wk, const float* __restrict__ wv,
                            const float* __restrict__ wo,
                            u16* __restrict__ xb, u16* __restrict__ wcat, u16* __restrict__ wob,
                            float* __restrict__ cosT, float* __restrict__ sinT) {
  const long id = (long)blockIdx.x * 256 + threadIdx.x;
  if (id < 262144) {                       // wq -> wcat rows 0..1023
    cvt4(wq + id * 4, wcat + id * 4);
  } else if (id < 327680) {                // wk -> wcat rows 1024..1279
    const long i = id - 262144;
    cvt4(wk + i * 4, wcat + 1048576 + i * 4);
  } else if (id < 393216) {                // wv -> wcat rows 1280..1535
    const long i = id - 327680;
    cvt4(wv + i * 4, wcat + 1310720 + i * 4);
  } else if (id < 655360) {                // wo
    const long i = id - 393216;
    cvt4(wo + i * 4, wob + i * 4);
  } else if (id < 671744) {                // trig tables, 4 entries per id
    const long t = id - 655360;
#pragma unroll
    for (int u = 0; u < 4; ++u) {
      const long idx = t * 4 + u;
      const int s = (int)(idx >> 5), j = (int)(idx & 31);
      const double invd = exp(-(double)j * 0.2878231366242558);  // ln(10000)/32
      const float a = (float)s * (float)invd;
      cosT[idx] = cosf(a);
      sinT[idx] = sinf(a);
    }
  } else {                                 // x
    const long i = id - 671744;
    cvt4(x + i * 4, xb + i * 4);
  }
}

// ---------------- fused QKV projection GEMM (BK=64, dbuf, swizzled, XCD-chunked) ----------------
// flat grid 384: arowBlk=(bid&7)*4+((bid>>3)&3), wcolBlk=bid>>5.
// V blocks (wcolBlk >= 10) use swapped MFMA operands -> transposed acc -> coalesced V^T store.

__global__ __launch_bounds__(256, 2) void gemm_qkv_kernel(
    const u16* __restrict__ A, const u16* __restrict__ W,
    u16* __restrict__ qo, u16* __restrict__ ko, u16* __restrict__ vto,
    const float* __restrict__ cosT, const float* __restrict__ sinT) {
  const int K = 1024;
  __shared__ __align__(16) u16 As[2][128 * 64];
  __shared__ __align__(16) u16 Bs[2][128 * 64];
  const int tid = threadIdx.x;
  const int lane = tid & 63;
  const int wave = tid >> 6;
  const int g = lane >> 4, l15 = lane & 15;
  const int wr = wave >> 1, wc = wave & 1;
  const int bid = blockIdx.x;
  const int arowBlk = (bid & 7) * 4 + ((bid >> 3) & 3);
  const int wcolBlk = bid >> 5;
  const long arow0 = (long)arowBlk * 128;
  const long wrow0 = (long)wcolBlk * 128;
  const u16* Ab = A + arow0 * K;
  const u16* Wb = W + wrow0 * K;
  const bool isV = (wcolBlk >= 10);

  auto STAGE = [&](int buf, int k0) {
#pragma unroll
    for (int i = 0; i < 4; ++i) {
      const int lbase = i * 256 + wave * 64;
      const int c = lbase + lane;
      const int r = c >> 3, c8 = c & 7;
      const int cs = (c8 ^ (r & 7)) * 8;       // inverse-swizzled source (rule #21)
      g2l16(Ab + (long)r * K + k0 + cs, (char*)As[buf] + lbase * 16);
      g2l16(Wb + (long)r * K + k0 + cs, (char*)Bs[buf] + lbase * 16);
    }
  };

  f32x4 acc[4][4] = {};
  int cur = 0;
  STAGE(0, 0);

  for (int k0 = 0; k0 < K; k0 += 64) {
    if (k0 + 64 < K) {
      STAGE(cur ^ 1, k0 + 64);
      asm volatile("s_waitcnt vmcnt(8)" ::: "memory");   // cur's 8 loads done; next 8 in flight
    } else {
      asm volatile("s_waitcnt vmcnt(0)" ::: "memory");
    }
    __builtin_amdgcn_s_barrier();
#pragma unroll
    for (int ks = 0; ks < 2; ++ks) {
      s16x8 af[4], bfr[4];
#pragma unroll
      for (int m = 0; m < 4; ++m) {
        const int row = wr * 64 + m * 16 + l15;
        af[m] = *(const s16x8*)((const char*)As[cur] + row * 128 + (((ks * 4 + g) ^ (row & 7)) << 4));
      }
#pragma unroll
      for (int n = 0; n < 4; ++n) {
        const int row = wc * 64 + n * 16 + l15;
        bfr[n] = *(const s16x8*)((const char*)Bs[cur] + row * 128 + (((ks * 4 + g) ^ (row & 7)) << 4));
      }
      __builtin_amdgcn_s_setprio(1);
      if (!isV) {
#pragma unroll
        for (int m = 0; m < 4; ++m)
#pragma unroll
          for (int n = 0; n < 4; ++n)
            acc[m][n] = __builtin_amdgcn_mfma_f32_16x16x32_bf16(af[m], bfr[n], acc[m][n], 0, 0, 0);
      } else {
        // swapped: acc[mw][nx], rows = W-dim (d), cols = X-dim (s)
#pragma unroll
        for (int m = 0; m < 4; ++m)
#pragma unroll
          for (int n = 0; n < 4; ++n)
            acc[m][n] = __builtin_amdgcn_mfma_f32_16x16x32_bf16(bfr[m], af[n], acc[m][n], 0, 0, 0);
      }
      __builtin_amdgcn_s_setprio(0);
    }
    __builtin_amdgcn_s_barrier();
    cur ^= 1;
  }

  const int colBase = (int)wrow0 + wc * 64;
  const int j0 = l15;
  const float QSCALE = 0.18033688011112042f;   // 0.125 * log2(e): softmax done in base 2

  if (colBase < 1024) {                       // ---- Q: rope + scale ----
    const int h2 = colBase >> 6;
#pragma unroll
    for (int m = 0; m < 4; ++m) {
      const int grow = (int)arow0 + wr * 64 + m * 16 + g * 4;
#pragma unroll
      for (int r = 0; r < 4; ++r) {
        const int row = grow + r;
        const int s = row & 2047, bb = row >> 11;
        const long ob = (((long)(bb * 16 + h2)) * 2048 + s) * 64;
        const float c0 = cosT[s * 32 + j0],      s0 = sinT[s * 32 + j0];
        const float c1 = cosT[s * 32 + 16 + j0], s1 = sinT[s * 32 + 16 + j0];
        qo[ob + j0]      = f2bf((acc[m][0][r] * c0 - acc[m][2][r] * s0) * QSCALE);
        qo[ob + 16 + j0] = f2bf((acc[m][1][r] * c1 - acc[m][3][r] * s1) * QSCALE);
        qo[ob + 32 + j0] = f2bf((acc[m][2][r] * c0 + acc[m][0][r] * s0) * QSCALE);
        qo[ob + 48 + j0] = f2bf((acc[m][3][r] * c1 + acc[m][1][r] * s1) * QSCALE);
      }
    }
  } else if (colBase < 1280) {                // ---- K: rope ----
    const int kvh2 = (colBase - 1024) >> 6;
#pragma unroll
    for (int m = 0; m < 4; ++m) {
      const int grow = (int)arow0 + wr * 64 + m * 16 + g * 4;
#pragma unroll
      for (int r = 0; r < 4; ++r) {
        const int row = grow + r;
        const int s = row & 2047, bb = row >> 11;
        const long ob = (((long)(bb * 4 + kvh2)) * 2048 + s) * 64;
        const float c0 = cosT[s * 32 + j0],      s0 = sinT[s * 32 + j0];
        const float c1 = cosT[s * 32 + 16 + j0], s1 = sinT[s * 32 + 16 + j0];
        ko[ob + j0]      = f2bf(acc[m][0][r] * c0 - acc[m][2][r] * s0);
        ko[ob + 16 + j0] = f2bf(acc[m][1][r] * c1 - acc[m][3][r] * s1);
        ko[ob + 32 + j0] = f2bf(acc[m][2][r] * c0 + acc[m][0][r] * s0);
        ko[ob + 48 + j0] = f2bf(acc[m][3][r] * c1 + acc[m][1][r] * s1);
      }
    }
  } else {                                    // ---- V (swapped acc): coalesced V^T store ----
    const int kvh2 = (colBase - 1280) >> 6;
    const int bb = (int)(arow0 >> 11);
    const int sBase = (int)(arow0 & 2047) + wr * 64;
    const long vrow0 = ((long)(bb * 4 + kvh2)) * 64;
#pragma unroll
    for (int mw = 0; mw < 4; ++mw) {          // W 16-row group (d)
      const int d0 = mw * 16 + g * 4;
#pragma unroll
      for (int r = 0; r < 4; ++r) {
        const long db = (vrow0 + d0 + r) * 2048;
#pragma unroll
        for (int nx = 0; nx < 4; ++nx)        // X 16-row group (s)
          vto[db + sBase + nx * 16 + l15] = f2bf(acc[mw][nx][r]);
      }
    }
  }
}

// ---------------- output projection GEMM (BK=64, dbuf, swizzled, XCD-chunked, fp32 out) ----------------

__global__ __launch_bounds__(256, 2) void gemm_out_kernel(
    const u16* __restrict__ A, const u16* __restrict__ W, float* __restrict__ Y) {
  const int K = 1024, N = 1024;
  __shared__ __align__(16) u16 As[2][128 * 64];
  __shared__ __align__(16) u16 Bs[2][128 * 64];
  const int tid = threadIdx.x;
  const int lane = tid & 63;
  const int wave = tid >> 6;
  const int g = lane >> 4, l15 = lane & 15;
  const int wr = wave >> 1, wc = wave & 1;
  const int bid = blockIdx.x;
  const int arowBlk = (bid & 7) * 4 + ((bid >> 3) & 3);
  const int wcolBlk = bid >> 5;
  const long arow0 = (long)arowBlk * 128;
  const long wrow0 = (long)wcolBlk * 128;
  const u16* Ab = A + arow0 * K;
  const u16* Wb = W + wrow0 * K;

  auto STAGE = [&](int buf, int k0) {
#pragma unroll
    for (int i = 0; i < 4; ++i) {
      const int lbase = i * 256 + wave * 64;
      const int c = lbase + lane;
      const int r = c >> 3, c8 = c & 7;
      const int cs = (c8 ^ (r & 7)) * 8;
      g2l16(Ab + (long)r * K + k0 + cs, (char*)As[buf] + lbase * 16);
      g2l16(Wb + (long)r * K + k0 + cs, (char*)Bs[buf] + lbase * 16);
    }
  };

  f32x4 acc[4][4] = {};
  int cur = 0;
  STAGE(0, 0);

  for (int k0 = 0; k0 < K; k0 += 64) {
    if (k0 + 64 < K) {
      STAGE(cur ^ 1, k0 + 64);
      asm volatile("s_waitcnt vmcnt(8)" ::: "memory");
    } else {
      asm volatile("s_waitcnt vmcnt(0)" ::: "memory");
    }
    __builtin_amdgcn_s_barrier();
#pragma unroll
    for (int ks = 0; ks < 2; ++ks) {
      s16x8 af[4], bfr[4];
#pragma unroll
      for (int m = 0; m < 4; ++m) {
        const int row = wr * 64 + m * 16 + l15;
        af[m] = *(const s16x8*)((const char*)As[cur] + row * 128 + (((ks * 4 + g) ^ (row & 7)) << 4));
      }
#pragma unroll
      for (int n = 0; n < 4; ++n) {
        const int row = wc * 64 + n * 16 + l15;
        bfr[n] = *(const s16x8*)((const char*)Bs[cur] + row * 128 + (((ks * 4 + g) ^ (row & 7)) << 4));
      }
      __builtin_amdgcn_s_setprio(1);
#pragma unroll
      for (int m = 0; m < 4; ++m)
#pragma unroll
        for (int n = 0; n < 4; ++n)
          acc[m][n] = __builtin_amdgcn_mfma_f32_16x16x32_bf16(af[m], bfr[n], acc[m][n], 0, 0, 0);
      __builtin_amdgcn_s_setprio(0);
    }
    __builtin_amdgcn_s_barrier();
    cur ^= 1;
  }

#pragma unroll
  for (int m = 0; m < 4; ++m)
#pragma unroll
    for (int n = 0; n < 4; ++n) {
      const long gr0 = arow0 + wr * 64 + m * 16 + g * 4;
      const long gc = wrow0 + wc * 64 + n * 16 + l15;
#pragma unroll
      for (int r = 0; r < 4; ++r)
        Y[(gr0 + r) * N + gc] = acc[m][n][r];
    }
}

// ---------------- flash attention (triple-buffered, 1 barrier/tile, swapped QK^T) ----------------
// grid 512 flat (XCD-chunked remap); block does q-tiles pr and 31-pr (balanced, 33 kv-tiles).
// Triple-buffer safety (single top barrier): at iteration kt a wave stages buf (kt+1)%3.
// Any lagging wave has passed barrier kt-1, so it reads only (kt-1)%3 or kt%3 — both
// distinct from (kt+1)%3 mod 3. (Double-buffer would alias (kt+1)%2 == (kt-1)%2.)

__global__ __launch_bounds__(256, 2) void flash_kernel(
    const u16* __restrict__ qg,   // [B][16][S][64]
    const u16* __restrict__ kg,   // [B][4][S][64]
    const u16* __restrict__ vtg,  // [B][4][64][S]
    u16* __restrict__ og) {       // [B][S][1024]
  const int tid = threadIdx.x, lane = tid & 63, w = tid >> 6;
  const int g = lane >> 4, l15 = lane & 15;

  const int bid = blockIdx.x;
  const int lid = (bid & 7) * 64 + (bid >> 3);
  const int pr = lid & 15, h = (lid >> 4) & 15, b = lid >> 8;
  const int kvh = h >> 2;

  __shared__ __align__(16) u16 Kl[3][64 * 64];   // [kv][d], 16B-chunk XOR swizzle
  __shared__ __align__(16) u16 Vl[3][64 * 64];   // [d][kv], 16B-chunk XOR swizzle
  __shared__ __align__(16) u16 Pl[4][16 * 64];   // per-wave P [q][kv], 16B-chunk XOR swizzle

  const u16* Kp = kg  + ((long)(b * 4 + kvh)) * 2048 * 64;
  const u16* Vp = vtg + ((long)(b * 4 + kvh)) * 64 * 2048;

  auto STAGE = [&](int buf, int kt) {
#pragma unroll
    for (int j = 0; j < 2; ++j) {
      const int lbase = j * 256 + w * 64;          // wave-uniform chunk base
      const int c = lbase + lane;
      const int row = c >> 3, c8 = c & 7;
      const int cs = (c8 ^ (row & 7)) * 8;         // inverse-swizzled source (rule #21)
      g2l16(Kp + ((long)(kt * 64 + row)) * 64 + cs, (char*)Kl[buf] + lbase * 16);
      g2l16(Vp + (long)row * 2048 + kt * 64 + cs,  (char*)Vl[buf] + lbase * 16);
    }
  };

#pragma unroll 1
  for (int pass = 0; pass < 2; ++pass) {
    const int qt = pass ? (31 - pr) : pr;
    const u16* Qp = qg + (((long)(b * 16 + h)) * 2048 + qt * 64 + w * 16) * 64;
    const s16x8 qf0 = *(const s16x8*)(Qp + l15 * 64 + g * 8);
    const s16x8 qf1 = *(const s16x8*)(Qp + l15 * 64 + 32 + g * 8);

    f32x4 of[4] = {};
    float m = -1e30f, lsum = 0.f;
    const int qrow = qt * 64 + w * 16 + l15;

    int cb = 0;                 // buffer for current tile (kt % 3)
    STAGE(0, 0);

#pragma unroll 1
    for (int kt = 0; kt <= qt; ++kt) {
      const int nb = (cb == 2) ? 0 : cb + 1;
      if (kt < qt) {
        STAGE(nb, kt + 1);
        asm volatile("s_waitcnt vmcnt(4)" ::: "memory");   // cur's 4 loads done; next 4 in flight
      } else {
        asm volatile("s_waitcnt vmcnt(0)" ::: "memory");
      }
      __builtin_amdgcn_s_barrier();                        // single barrier per tile
      const u16* Kb = Kl[cb];
      const u16* Vb = Vl[cb];

      // S^T tile: mfma(K, Q) -> C[kv][q], lane owns q = l15, 16 kv values in regs
      f32x4 sf[4] = {};
      __builtin_amdgcn_s_setprio(1);
#pragma unroll
      for (int ks = 0; ks < 2; ++ks) {
        const s16x8 qv = ks ? qf1 : qf0;
#pragma unroll
        for (int fn = 0; fn < 4; ++fn) {
          const int row = fn * 16 + l15;
          const s16x8 kf = *(const s16x8*)((const char*)Kb + row * 128 + (((ks * 4 + g) ^ (row & 7)) << 4));
          sf[fn] = __builtin_amdgcn_mfma_f32_16x16x32_bf16(kf, qv, sf[fn], 0, 0, 0);
        }
      }
      __builtin_amdgcn_s_setprio(0);

      // causal mask; row max via max3-friendly triples (+2 shuffles)
      const bool diag = (kt == qt);
      float p[16];
#pragma unroll
      for (int fn = 0; fn < 4; ++fn)
#pragma unroll
        for (int r = 0; r < 4; ++r) {
          float sv = sf[fn][r];
          if (diag) {
            const int kv = kt * 64 + fn * 16 + 4 * g + r;
            if (kv > qrow) sv = -1e30f;
          }
          p[fn * 4 + r] = sv;
        }
      const float t0 = fmaxf(fmaxf(p[0], p[1]), p[2]);
      const float t1 = fmaxf(fmaxf(p[3], p[4]), p[5]);
      const float t2 = fmaxf(fmaxf(p[6], p[7]), p[8]);
      const float t3 = fmaxf(fmaxf(p[9], p[10]), p[11]);
      const float t4 = fmaxf(fmaxf(p[12], p[13]), p[14]);
      float mx = fmaxf(fmaxf(fmaxf(t0, t1), t2), fmaxf(fmaxf(t3, t4), p[15]));
      mx = fmaxf(mx, __shfl_xor(mx, 16));
      mx = fmaxf(mx, __shfl_xor(mx, 32));

      // defer-max (T13): rescale only when max grew by > 11 (base-2)
      if (!__all(mx - m <= 11.0f)) {
        const float mn = fmaxf(m, mx);
        const float al = exp2fast(m - mn);
        m = mn;
        lsum *= al;
        float alq[4];
#pragma unroll
        for (int r = 0; r < 4; ++r) alq[r] = __shfl(al, 4 * g + r);
#pragma unroll
        for (int fd = 0; fd < 4; ++fd)
#pragma unroll
          for (int r = 0; r < 4; ++r) of[fd][r] *= alq[r];
      }

#pragma unroll
      for (int i = 0; i < 16; ++i) p[i] = exp2fast(p[i] - m);
      const float s0 = (p[0] + p[1]) + (p[2] + p[3]);
      const float s1 = (p[4] + p[5]) + (p[6] + p[7]);
      const float s2 = (p[8] + p[9]) + (p[10] + p[11]);
      const float s3 = (p[12] + p[13]) + (p[14] + p[15]);
      float rs = (s0 + s1) + (s2 + s3);
      rs += __shfl_xor(rs, 16);
      rs += __shfl_xor(rs, 32);
      lsum += rs;

      // P -> per-wave LDS [q][kv], 128B row, 16B-chunk XOR (r2 pattern: 0 conflicts).
      // kv bytes fn*32+8g..+8 -> chunk 2fn+(g>>1), low (g&1)*8; b64 via cvt_pk.
      char* Pw = (char*)Pl[w] + l15 * 128;
#pragma unroll
      for (int fn = 0; fn < 4; ++fn) {
        const u32x2 v2 = {cvt_pk(p[fn * 4 + 0], p[fn * 4 + 1]),
                          cvt_pk(p[fn * 4 + 2], p[fn * 4 + 3])};
        *(u32x2*)(Pw + ((((2 * fn + (g >> 1)) ^ (l15 & 7))) << 4) + ((g & 1) * 8)) = v2;
      }

      // O += P @ V : A-frag = P rows (q), B-frag = V^T rows (d)
      __builtin_amdgcn_s_setprio(1);
#pragma unroll
      for (int ks = 0; ks < 2; ++ks) {
        const s16x8 pa = *(const s16x8*)(Pw + (((ks * 4 + g) ^ (l15 & 7)) << 4));
#pragma unroll
        for (int fd = 0; fd < 4; ++fd) {
          const int vrow = fd * 16 + l15;
          const s16x8 vf = *(const s16x8*)((const char*)Vb + vrow * 128 + (((ks * 4 + g) ^ (vrow & 7)) << 4));
          of[fd] = __builtin_amdgcn_mfma_f32_16x16x32_bf16(pa, vf, of[fd], 0, 0, 0);
        }
      }
      __builtin_amdgcn_s_setprio(0);

      cb = nb;                 // no end-of-tile barrier (triple-buffer safety above)
    }

    __syncthreads();           // protect buffers across passes

    // normalize + store; of rows are q_local = 4g+r, stats live at lane 4g+r
    float linv[4];
#pragma unroll
    for (int r = 0; r < 4; ++r) linv[r] = 1.0f / __shfl(lsum, 4 * g + r);
    const long orow0 = (long)b * 2048 + qt * 64 + w * 16 + 4 * g;
#pragma unroll
    for (int r = 0; r < 4; ++r) {
      const long gb = (orow0 + r) * 1024 + h * 64;
#pragma unroll
      for (int fd = 0; fd < 4; ++fd)
        og[gb + fd * 16 + l15] = f2bf(of[fd][r] * linv[r]);
    }
  }
}

// ---------------- launch ----------------

extern "C" void kernel_launch(void* const* d_in, const int* in_sizes, int n_in,
                              void* d_out, int out_size, void* d_ws, size_t ws_size,
                              hipStream_t stream) {
  (void)in_sizes; (void)n_in; (void)out_size; (void)ws_size;
  const float* x  = (const float*)d_in[0];
  const float* wq = (const float*)d_in[1];
  const float* wk = (const float*)d_in[2];
  const float* wv = (const float*)d_in[3];
  const float* wo = (const float*)d_in[4];
  float* out = (float*)d_out;

  char* p = (char*)d_ws;
  auto alloc = [&](size_t bytes) { char* r = p; p += (bytes + 255) & ~(size_t)255; return r; };

  u16* xb    = (u16*)alloc(4096ull * 1024 * 2);
  u16* wcat  = (u16*)alloc(1536ull * 1024 * 2);   // [wq; wk; wv]
  u16* wob   = (u16*)alloc(1024ull * 1024 * 2);
  u16* qrb   = (u16*)alloc(4096ull * 1024 * 2);   // [B][16][S][64]
  u16* krb   = (u16*)alloc(4096ull * 256 * 2);    // [B][4][S][64]
  u16* vtb   = (u16*)alloc(4096ull * 256 * 2);    // [B][4][64][S]
  u16* aob   = (u16*)alloc(4096ull * 1024 * 2);   // [B][S][1024]
  float* cosT = (float*)alloc(2048ull * 32 * 4);
  float* sinT = (float*)alloc(2048ull * 32 * 4);

  // single fused prep: weight/x conversions + trig tables
  prep_kernel<<<6720, 256, 0, stream>>>(x, wq, wk, wv, wo, xb, wcat, wob, cosT, sinT);

  // fused QKV projection + rope + layout (XCD-chunked flat grid)
  gemm_qkv_kernel<<<384, 256, 0, stream>>>(xb, wcat, qrb, krb, vtb, cosT, sinT);

  // causal GQA flash attention (balanced pairs, triple-buffered)
  flash_kernel<<<512, 256, 0, stream>>>(qrb, krb, vtb, aob);

  // output projection (fp32 out, XCD-chunked flat grid)
  gemm_out_kernel<<<256, 256, 0, stream>>>(aob, wob, out);
}

// Round 11
// 162.171 us; speedup vs baseline: 1.1961x; 1.0290x over previous
//
#include <hip/hip_runtime.h>
#include <stdint.h>

typedef unsigned short u16;
typedef __attribute__((ext_vector_type(8))) short s16x8;   // bf16x8 MFMA frag (4 VGPRs)
typedef __attribute__((ext_vector_type(4))) float f32x4;   // MFMA C/D frag
typedef __attribute__((ext_vector_type(4))) unsigned short u16x4;
typedef __attribute__((ext_vector_type(2))) unsigned int u32x2;

// ---------------- helpers ----------------

__device__ __forceinline__ u16 f2bf(float f) {
  unsigned u = __float_as_uint(f);
  unsigned r = (u + 0x7fffu + ((u >> 16) & 1u)) >> 16;   // RNE
  return (u16)r;
}
__device__ __forceinline__ unsigned cvt_pk(float lo, float hi) {
  unsigned r;
  asm("v_cvt_pk_bf16_f32 %0, %1, %2" : "=v"(r) : "v"(lo), "v"(hi));
  return r;
}
__device__ __forceinline__ float exp2fast(float x) {
  return __builtin_amdgcn_exp2f(x);   // v_exp_f32: D = 2^S0
}

typedef const __attribute__((address_space(1))) unsigned int* gas_ptr;
typedef __attribute__((address_space(3))) unsigned int* las_ptr;

__device__ __forceinline__ void g2l16(const void* g, void* l) {
  __builtin_amdgcn_global_load_lds((gas_ptr)g, (las_ptr)l, 16, 0, 0);
}

__device__ __forceinline__ void cvt4(const float* __restrict__ in, u16* __restrict__ out) {
  const f32x4 v = *(const f32x4*)in;
  u16x4 o;
  o[0] = f2bf(v[0]); o[1] = f2bf(v[1]); o[2] = f2bf(v[2]); o[3] = f2bf(v[3]);
  *(u16x4*)out = o;
}

// ---------------- fused prep: all bf16 conversions + trig tables ----------------

__global__ void prep_kernel(const float* __restrict__ x,  const float* __restrict__ wq,
                            const float* __restrict__ wk, const float* __restrict__ wv,
                            const float* __restrict__ wo,
                            u16* __restrict__ xb, u16* __restrict__ wcat, u16* __restrict__ wob,
                            float* __restrict__ cosT, float* __restrict__ sinT) {
  const long id = (long)blockIdx.x * 256 + threadIdx.x;
  if (id < 262144) {                       // wq -> wcat rows 0..1023
    cvt4(wq + id * 4, wcat + id * 4);
  } else if (id < 327680) {                // wk -> wcat rows 1024..1279
    const long i = id - 262144;
    cvt4(wk + i * 4, wcat + 1048576 + i * 4);
  } else if (id < 393216) {                // wv -> wcat rows 1280..1535
    const long i = id - 327680;
    cvt4(wv + i * 4, wcat + 1310720 + i * 4);
  } else if (id < 655360) {                // wo
    const long i = id - 393216;
    cvt4(wo + i * 4, wob + i * 4);
  } else if (id < 671744) {                // trig tables, 4 entries per id
    const long t = id - 655360;
#pragma unroll
    for (int u = 0; u < 4; ++u) {
      const long idx = t * 4 + u;
      const int s = (int)(idx >> 5), j = (int)(idx & 31);
      const double invd = exp(-(double)j * 0.2878231366242558);  // ln(10000)/32
      const float a = (float)s * (float)invd;
      cosT[idx] = cosf(a);
      sinT[idx] = sinf(a);
    }
  } else {                                 // x
    const long i = id - 671744;
    cvt4(x + i * 4, xb + i * 4);
  }
}

// ---------------- fused QKV projection GEMM (128x64 tile, BK=64, dbuf, swizzled) ----------------
// grid 768 = 32 M-blocks x 24 N-blocks; 4 waves split 4x1 on M (wave = 32 rows x 64 cols).
// Each 64-col tile is exactly one head -> RoPE pairing stays in-register.
// V blocks (wcolBlk >= 20) use swapped MFMA operands -> transposed acc -> coalesced V^T store.

__global__ __launch_bounds__(256, 3) void gemm_qkv_kernel(
    const u16* __restrict__ A, const u16* __restrict__ W,
    u16* __restrict__ qo, u16* __restrict__ ko, u16* __restrict__ vto,
    const float* __restrict__ cosT, const float* __restrict__ sinT) {
  const int K = 1024;
  __shared__ __align__(16) u16 As[2][128 * 64];   // 32 KB
  __shared__ __align__(16) u16 Bs[2][64 * 64];    // 16 KB
  const int tid = threadIdx.x;
  const int lane = tid & 63;
  const int wave = tid >> 6;
  const int g = lane >> 4, l15 = lane & 15;
  const int bid = blockIdx.x;
  const int arowBlk = bid & 31;
  const int wcolBlk = bid >> 5;                   // 0..23
  const long arow0 = (long)arowBlk * 128;
  const long wrow0 = (long)wcolBlk * 64;
  const u16* Ab = A + arow0 * K;
  const u16* Wb = W + wrow0 * K;
  const bool isV = (wcolBlk >= 20);

  auto STAGE = [&](int buf, int k0) {
#pragma unroll
    for (int i = 0; i < 4; ++i) {                 // A: 128x64
      const int lbase = i * 256 + wave * 64;
      const int c = lbase + lane;
      const int r = c >> 3, c8 = c & 7;
      const int cs = (c8 ^ (r & 7)) * 8;          // inverse-swizzled source (rule #21)
      g2l16(Ab + (long)r * K + k0 + cs, (char*)As[buf] + lbase * 16);
    }
#pragma unroll
    for (int i = 0; i < 2; ++i) {                 // B: 64x64
      const int lbase = i * 256 + wave * 64;
      const int c = lbase + lane;
      const int r = c >> 3, c8 = c & 7;
      const int cs = (c8 ^ (r & 7)) * 8;
      g2l16(Wb + (long)r * K + k0 + cs, (char*)Bs[buf] + lbase * 16);
    }
  };

  f32x4 acc[8] = {};   // normal: acc[m*4+n] (m:0..1, n:0..3); isV: acc[nw*2+mx]
  int cur = 0;
  STAGE(0, 0);

  for (int k0 = 0; k0 < K; k0 += 64) {
    if (k0 + 64 < K) {
      STAGE(cur ^ 1, k0 + 64);
      asm volatile("s_waitcnt vmcnt(6)" ::: "memory");   // cur's 6 loads done; next 6 in flight
    } else {
      asm volatile("s_waitcnt vmcnt(0)" ::: "memory");
    }
    __builtin_amdgcn_s_barrier();
#pragma unroll
    for (int ks = 0; ks < 2; ++ks) {
      s16x8 af[2], bfr[4];
#pragma unroll
      for (int m = 0; m < 2; ++m) {
        const int row = wave * 32 + m * 16 + l15;
        af[m] = *(const s16x8*)((const char*)As[cur] + row * 128 + (((ks * 4 + g) ^ (row & 7)) << 4));
      }
#pragma unroll
      for (int n = 0; n < 4; ++n) {
        const int row = n * 16 + l15;
        bfr[n] = *(const s16x8*)((const char*)Bs[cur] + row * 128 + (((ks * 4 + g) ^ (row & 7)) << 4));
      }
      __builtin_amdgcn_s_setprio(1);
      if (!isV) {
#pragma unroll
        for (int m = 0; m < 2; ++m)
#pragma unroll
          for (int n = 0; n < 4; ++n)
            acc[m * 4 + n] = __builtin_amdgcn_mfma_f32_16x16x32_bf16(af[m], bfr[n], acc[m * 4 + n], 0, 0, 0);
      } else {
        // swapped: C rows = W-dim (d), cols = X-dim (s)
#pragma unroll
        for (int nw = 0; nw < 4; ++nw)
#pragma unroll
          for (int mx = 0; mx < 2; ++mx)
            acc[nw * 2 + mx] = __builtin_amdgcn_mfma_f32_16x16x32_bf16(bfr[nw], af[mx], acc[nw * 2 + mx], 0, 0, 0);
      }
      __builtin_amdgcn_s_setprio(0);
    }
    __builtin_amdgcn_s_barrier();
    cur ^= 1;
  }

  const int colBase = (int)wrow0;                // head-aligned (64-wide tile)
  const int j0 = l15;
  const float QSCALE = 0.18033688011112042f;    // 0.125 * log2(e): softmax in base 2

  if (colBase < 1024) {                         // ---- Q: rope + scale ----
    const int h2 = colBase >> 6;
#pragma unroll
    for (int m = 0; m < 2; ++m) {
      const int grow = (int)arow0 + wave * 32 + m * 16 + g * 4;
#pragma unroll
      for (int r = 0; r < 4; ++r) {
        const int row = grow + r;
        const int s = row & 2047, bb = row >> 11;
        const long ob = (((long)(bb * 16 + h2)) * 2048 + s) * 64;
        const float c0 = cosT[s * 32 + j0],      s0 = sinT[s * 32 + j0];
        const float c1 = cosT[s * 32 + 16 + j0], s1 = sinT[s * 32 + 16 + j0];
        qo[ob + j0]      = f2bf((acc[m * 4 + 0][r] * c0 - acc[m * 4 + 2][r] * s0) * QSCALE);
        qo[ob + 16 + j0] = f2bf((acc[m * 4 + 1][r] * c1 - acc[m * 4 + 3][r] * s1) * QSCALE);
        qo[ob + 32 + j0] = f2bf((acc[m * 4 + 2][r] * c0 + acc[m * 4 + 0][r] * s0) * QSCALE);
        qo[ob + 48 + j0] = f2bf((acc[m * 4 + 3][r] * c1 + acc[m * 4 + 1][r] * s1) * QSCALE);
      }
    }
  } else if (colBase < 1280) {                  // ---- K: rope ----
    const int kvh2 = (colBase - 1024) >> 6;
#pragma unroll
    for (int m = 0; m < 2; ++m) {
      const int grow = (int)arow0 + wave * 32 + m * 16 + g * 4;
#pragma unroll
      for (int r = 0; r < 4; ++r) {
        const int row = grow + r;
        const int s = row & 2047, bb = row >> 11;
        const long ob = (((long)(bb * 4 + kvh2)) * 2048 + s) * 64;
        const float c0 = cosT[s * 32 + j0],      s0 = sinT[s * 32 + j0];
        const float c1 = cosT[s * 32 + 16 + j0], s1 = sinT[s * 32 + 16 + j0];
        ko[ob + j0]      = f2bf(acc[m * 4 + 0][r] * c0 - acc[m * 4 + 2][r] * s0);
        ko[ob + 16 + j0] = f2bf(acc[m * 4 + 1][r] * c1 - acc[m * 4 + 3][r] * s1);
        ko[ob + 32 + j0] = f2bf(acc[m * 4 + 2][r] * c0 + acc[m * 4 + 0][r] * s0);
        ko[ob + 48 + j0] = f2bf(acc[m * 4 + 3][r] * c1 + acc[m * 4 + 1][r] * s1);
      }
    }
  } else {                                      // ---- V (swapped acc): coalesced V^T store ----
    const int kvh2 = (colBase - 1280) >> 6;
    const int bb = (int)(arow0 >> 11);
    const int sBase = ((int)arow0 & 2047) + wave * 32;
    const long vrow0 = ((long)(bb * 4 + kvh2)) * 64;
#pragma unroll
    for (int nw = 0; nw < 4; ++nw) {
#pragma unroll
      for (int r = 0; r < 4; ++r) {
        const int d = nw * 16 + 4 * g + r;
        const long db = (vrow0 + d) * 2048 + sBase;
#pragma unroll
        for (int mx = 0; mx < 2; ++mx)
          vto[db + mx * 16 + l15] = f2bf(acc[nw * 2 + mx][r]);
      }
    }
  }
}

// ---------------- output projection GEMM (128x64 tile, BK=64, dbuf, fp32 out) ----------------
// grid 512 = 32 M-blocks x 16 N-blocks; 4 waves split 4x1 on M.

__global__ __launch_bounds__(256, 2) void gemm_out_kernel(
    const u16* __restrict__ A, const u16* __restrict__ W, float* __restrict__ Y) {
  const int K = 1024, N = 1024;
  __shared__ __align__(16) u16 As[2][128 * 64];
  __shared__ __align__(16) u16 Bs[2][64 * 64];
  const int tid = threadIdx.x;
  const int lane = tid & 63;
  const int wave = tid >> 6;
  const int g = lane >> 4, l15 = lane & 15;
  const int bid = blockIdx.x;
  const int arowBlk = bid & 31;
  const int wcolBlk = bid >> 5;                  // 0..15
  const long arow0 = (long)arowBlk * 128;
  const long wrow0 = (long)wcolBlk * 64;
  const u16* Ab = A + arow0 * K;
  const u16* Wb = W + wrow0 * K;

  auto STAGE = [&](int buf, int k0) {
#pragma unroll
    for (int i = 0; i < 4; ++i) {
      const int lbase = i * 256 + wave * 64;
      const int c = lbase + lane;
      const int r = c >> 3, c8 = c & 7;
      const int cs = (c8 ^ (r & 7)) * 8;
      g2l16(Ab + (long)r * K + k0 + cs, (char*)As[buf] + lbase * 16);
    }
#pragma unroll
    for (int i = 0; i < 2; ++i) {
      const int lbase = i * 256 + wave * 64;
      const int c = lbase + lane;
      const int r = c >> 3, c8 = c & 7;
      const int cs = (c8 ^ (r & 7)) * 8;
      g2l16(Wb + (long)r * K + k0 + cs, (char*)Bs[buf] + lbase * 16);
    }
  };

  f32x4 acc[8] = {};
  int cur = 0;
  STAGE(0, 0);

  for (int k0 = 0; k0 < K; k0 += 64) {
    if (k0 + 64 < K) {
      STAGE(cur ^ 1, k0 + 64);
      asm volatile("s_waitcnt vmcnt(6)" ::: "memory");
    } else {
      asm volatile("s_waitcnt vmcnt(0)" ::: "memory");
    }
    __builtin_amdgcn_s_barrier();
#pragma unroll
    for (int ks = 0; ks < 2; ++ks) {
      s16x8 af[2], bfr[4];
#pragma unroll
      for (int m = 0; m < 2; ++m) {
        const int row = wave * 32 + m * 16 + l15;
        af[m] = *(const s16x8*)((const char*)As[cur] + row * 128 + (((ks * 4 + g) ^ (row & 7)) << 4));
      }
#pragma unroll
      for (int n = 0; n < 4; ++n) {
        const int row = n * 16 + l15;
        bfr[n] = *(const s16x8*)((const char*)Bs[cur] + row * 128 + (((ks * 4 + g) ^ (row & 7)) << 4));
      }
      __builtin_amdgcn_s_setprio(1);
#pragma unroll
      for (int m = 0; m < 2; ++m)
#pragma unroll
        for (int n = 0; n < 4; ++n)
          acc[m * 4 + n] = __builtin_amdgcn_mfma_f32_16x16x32_bf16(af[m], bfr[n], acc[m * 4 + n], 0, 0, 0);
      __builtin_amdgcn_s_setprio(0);
    }
    __builtin_amdgcn_s_barrier();
    cur ^= 1;
  }

#pragma unroll
  for (int m = 0; m < 2; ++m)
#pragma unroll
    for (int n = 0; n < 4; ++n) {
      const long gr0 = arow0 + wave * 32 + m * 16 + g * 4;
      const long gc = wrow0 + n * 16 + l15;
#pragma unroll
      for (int r = 0; r < 4; ++r)
        Y[(gr0 + r) * N + gc] = acc[m * 4 + n][r];
    }
}

// ---------------- flash attention (T15 pipeline: QKT(kt) | PV(kt-1) | softmax(kt)) ----------------
// grid 512 flat (XCD-chunked remap); block does q-tiles pr and 31-pr (balanced, 33 kv-tiles).
// K/V quad-buffered, 1 barrier/tile. Safety: at iter kt, waves span {kt, kt+1}; readers touch
// buffers {kt-1, kt} (lag) or {kt, kt+1}; staging targets kt+1 or kt+2 — mod 4, staging never
// collides with any live reader. P double-slot per wave (slot = kt&1), same-wave only.

__global__ __launch_bounds__(256, 2) void flash_kernel(
    const u16* __restrict__ qg,   // [B][16][S][64]
    const u16* __restrict__ kg,   // [B][4][S][64]
    const u16* __restrict__ vtg,  // [B][4][64][S]
    u16* __restrict__ og) {       // [B][S][1024]
  const int tid = threadIdx.x, lane = tid & 63, w = tid >> 6;
  const int g = lane >> 4, l15 = lane & 15;

  const int bid = blockIdx.x;
  const int lid = (bid & 7) * 64 + (bid >> 3);
  const int pr = lid & 15, h = (lid >> 4) & 15, b = lid >> 8;
  const int kvh = h >> 2;

  __shared__ __align__(16) u16 Kl[4][64 * 64];    // 32 KB, 16B-chunk XOR swizzle
  __shared__ __align__(16) u16 Vl[4][64 * 64];    // 32 KB
  __shared__ __align__(16) u16 Pl[4][2][16 * 64]; // 16 KB, per-wave double-slot

  const u16* Kp = kg  + ((long)(b * 4 + kvh)) * 2048 * 64;
  const u16* Vp = vtg + ((long)(b * 4 + kvh)) * 64 * 2048;

  auto STAGE = [&](int buf, int kt) {
#pragma unroll
    for (int j = 0; j < 2; ++j) {
      const int lbase = j * 256 + w * 64;          // wave-uniform chunk base
      const int c = lbase + lane;
      const int row = c >> 3, c8 = c & 7;
      const int cs = (c8 ^ (row & 7)) * 8;         // inverse-swizzled source (rule #21)
      g2l16(Kp + ((long)(kt * 64 + row)) * 64 + cs, (char*)Kl[buf] + lbase * 16);
      g2l16(Vp + (long)row * 2048 + kt * 64 + cs,  (char*)Vl[buf] + lbase * 16);
    }
  };

#pragma unroll 1
  for (int pass = 0; pass < 2; ++pass) {
    const int qt = pass ? (31 - pr) : pr;
    const u16* Qp = qg + (((long)(b * 16 + h)) * 2048 + qt * 64 + w * 16) * 64;
    const s16x8 qf0 = *(const s16x8*)(Qp + l15 * 64 + g * 8);
    const s16x8 qf1 = *(const s16x8*)(Qp + l15 * 64 + 32 + g * 8);

    f32x4 of[4] = {};
    float m = -1e30f, lsum = 0.f;
    const int qrow = qt * 64 + w * 16 + l15;

    STAGE(0, 0);

#pragma unroll 1
    for (int kt = 0; kt <= qt; ++kt) {
      if (kt < qt) {
        STAGE((kt + 1) & 3, kt + 1);
        asm volatile("s_waitcnt vmcnt(4)" ::: "memory");   // kt's 4 loads done; next 4 in flight
      } else {
        asm volatile("s_waitcnt vmcnt(0)" ::: "memory");
      }
      __builtin_amdgcn_s_barrier();                        // single barrier per tile
      const u16* Kb = Kl[kt & 3];

      // --- QK^T(kt): mfma(K, Q) -> C[kv][q]; lane owns q = l15, 16 kv in regs ---
      f32x4 sf[4] = {};
      __builtin_amdgcn_s_setprio(1);
#pragma unroll
      for (int ks = 0; ks < 2; ++ks) {
        const s16x8 qv = ks ? qf1 : qf0;
#pragma unroll
        for (int fn = 0; fn < 4; ++fn) {
          const int row = fn * 16 + l15;
          const s16x8 kf = *(const s16x8*)((const char*)Kb + row * 128 + (((ks * 4 + g) ^ (row & 7)) << 4));
          sf[fn] = __builtin_amdgcn_mfma_f32_16x16x32_bf16(kf, qv, sf[fn], 0, 0, 0);
        }
      }

      // --- PV(kt-1): independent of QKT results -> overlaps softmax below ---
      if (kt) {
        const u16* Vbp = Vl[(kt - 1) & 3];
        const char* Pr = (const char*)Pl[w][(kt - 1) & 1] + l15 * 128;
#pragma unroll
        for (int ks = 0; ks < 2; ++ks) {
          const s16x8 pa = *(const s16x8*)(Pr + (((ks * 4 + g) ^ (l15 & 7)) << 4));
#pragma unroll
          for (int fd = 0; fd < 4; ++fd) {
            const int vrow = fd * 16 + l15;
            const s16x8 vf = *(const s16x8*)((const char*)Vbp + vrow * 128 + (((ks * 4 + g) ^ (vrow & 7)) << 4));
            of[fd] = __builtin_amdgcn_mfma_f32_16x16x32_bf16(pa, vf, of[fd], 0, 0, 0);
          }
        }
      }
      __builtin_amdgcn_s_setprio(0);

      // --- softmax(kt) (VALU; overlaps PV's matrix-pipe time) ---
      const bool diag = (kt == qt);
      float p[16];
#pragma unroll
      for (int fn = 0; fn < 4; ++fn)
#pragma unroll
        for (int r = 0; r < 4; ++r) {
          float sv = sf[fn][r];
          if (diag) {
            const int kv = kt * 64 + fn * 16 + 4 * g + r;
            if (kv > qrow) sv = -1e30f;
          }
          p[fn * 4 + r] = sv;
        }
      const float t0 = fmaxf(fmaxf(p[0], p[1]), p[2]);
      const float t1 = fmaxf(fmaxf(p[3], p[4]), p[5]);
      const float t2 = fmaxf(fmaxf(p[6], p[7]), p[8]);
      const float t3 = fmaxf(fmaxf(p[9], p[10]), p[11]);
      const float t4 = fmaxf(fmaxf(p[12], p[13]), p[14]);
      float mx = fmaxf(fmaxf(fmaxf(t0, t1), t2), fmaxf(fmaxf(t3, t4), p[15]));
      mx = fmaxf(mx, __shfl_xor(mx, 16));
      mx = fmaxf(mx, __shfl_xor(mx, 32));

      // defer-max (T13): rescale only when max grew by > 11 (base-2). Reads `of` ->
      // naturally ordered after PV(kt-1) completes (rare path).
      if (!__all(mx - m <= 11.0f)) {
        const float mn = fmaxf(m, mx);
        const float al = exp2fast(m - mn);
        m = mn;
        lsum *= al;
        float alq[4];
#pragma unroll
        for (int r = 0; r < 4; ++r) alq[r] = __shfl(al, 4 * g + r);
#pragma unroll
        for (int fd = 0; fd < 4; ++fd)
#pragma unroll
          for (int r = 0; r < 4; ++r) of[fd][r] *= alq[r];
      }

#pragma unroll
      for (int i = 0; i < 16; ++i) p[i] = exp2fast(p[i] - m);
      const float s0 = (p[0] + p[1]) + (p[2] + p[3]);
      const float s1 = (p[4] + p[5]) + (p[6] + p[7]);
      const float s2 = (p[8] + p[9]) + (p[10] + p[11]);
      const float s3 = (p[12] + p[13]) + (p[14] + p[15]);
      float rs = (s0 + s1) + (s2 + s3);
      rs += __shfl_xor(rs, 16);
      rs += __shfl_xor(rs, 32);
      lsum += rs;

      // --- writeP(kt) -> slot kt&1 (b64 cvt_pk pairs) ---
      char* Pw = (char*)Pl[w][kt & 1] + l15 * 128;
#pragma unroll
      for (int fn = 0; fn < 4; ++fn) {
        const u32x2 v2 = {cvt_pk(p[fn * 4 + 0], p[fn * 4 + 1]),
                          cvt_pk(p[fn * 4 + 2], p[fn * 4 + 3])};
        *(u32x2*)(Pw + ((((2 * fn + (g >> 1)) ^ (l15 & 7))) << 4) + ((g & 1) * 8)) = v2;
      }
    }

    // --- epilogue PV(qt) ---
    {
      const u16* Vbp = Vl[qt & 3];
      const char* Pr = (const char*)Pl[w][qt & 1] + l15 * 128;
      __builtin_amdgcn_s_setprio(1);
#pragma unroll
      for (int ks = 0; ks < 2; ++ks) {
        const s16x8 pa = *(const s16x8*)(Pr + (((ks * 4 + g) ^ (l15 & 7)) << 4));
#pragma unroll
        for (int fd = 0; fd < 4; ++fd) {
          const int vrow = fd * 16 + l15;
          const s16x8 vf = *(const s16x8*)((const char*)Vbp + vrow * 128 + (((ks * 4 + g) ^ (vrow & 7)) << 4));
          of[fd] = __builtin_amdgcn_mfma_f32_16x16x32_bf16(pa, vf, of[fd], 0, 0, 0);
        }
      }
      __builtin_amdgcn_s_setprio(0);
    }

    __syncthreads();           // all waves done reading buffers before next pass restages

    // normalize + store; of rows are q_local = 4g+r, stats live at lane 4g+r
    float linv[4];
#pragma unroll
    for (int r = 0; r < 4; ++r) linv[r] = 1.0f / __shfl(lsum, 4 * g + r);
    const long orow0 = (long)b * 2048 + qt * 64 + w * 16 + 4 * g;
#pragma unroll
    for (int r = 0; r < 4; ++r) {
      const long gb = (orow0 + r) * 1024 + h * 64;
#pragma unroll
      for (int fd = 0; fd < 4; ++fd)
        og[gb + fd * 16 + l15] = f2bf(of[fd][r] * linv[r]);
    }
  }
}

// ---------------- launch ----------------

extern "C" void kernel_launch(void* const* d_in, const int* in_sizes, int n_in,
                              void* d_out, int out_size, void* d_ws, size_t ws_size,
                              hipStream_t stream) {
  (void)in_sizes; (void)n_in; (void)out_size; (void)ws_size;
  const float* x  = (const float*)d_in[0];
  const float* wq = (const float*)d_in[1];
  const float* wk = (const float*)d_in[2];
  const float* wv = (const float*)d_in[3];
  const float* wo = (const float*)d_in[4];
  float* out = (float*)d_out;

  char* p = (char*)d_ws;
  auto alloc = [&](size_t bytes) { char* r = p; p += (bytes + 255) & ~(size_t)255; return r; };

  u16* xb    = (u16*)alloc(4096ull * 1024 * 2);
  u16* wcat  = (u16*)alloc(1536ull * 1024 * 2);   // [wq; wk; wv]
  u16* wob   = (u16*)alloc(1024ull * 1024 * 2);
  u16* qrb   = (u16*)alloc(4096ull * 1024 * 2);   // [B][16][S][64]
  u16* krb   = (u16*)alloc(4096ull * 256 * 2);    // [B][4][S][64]
  u16* vtb   = (u16*)alloc(4096ull * 256 * 2);    // [B][4][64][S]
  u16* aob   = (u16*)alloc(4096ull * 1024 * 2);   // [B][S][1024]
  float* cosT = (float*)alloc(2048ull * 32 * 4);
  float* sinT = (float*)alloc(2048ull * 32 * 4);

  // single fused prep: weight/x conversions + trig tables
  prep_kernel<<<6720, 256, 0, stream>>>(x, wq, wk, wv, wo, xb, wcat, wob, cosT, sinT);

  // fused QKV projection + rope + layout (128x64 tiles, 3 blocks/CU)
  gemm_qkv_kernel<<<768, 256, 0, stream>>>(xb, wcat, qrb, krb, vtb, cosT, sinT);

  // causal GQA flash attention (T15 pipelined, quad-buffered)
  flash_kernel<<<512, 256, 0, stream>>>(qrb, krb, vtb, aob);

  // output projection (fp32 out, 128x64 tiles)
  gemm_out_kernel<<<512, 256, 0, stream>>>(aob, wob, out);
}